// Round 1
// baseline (363.936 us; speedup 1.0000x reference)
//
#include <hip/hip_runtime.h>
#include <math.h>

// Problem sizes: B=16, Cin=1, CH=32, N0=128, F=512, G=4, N1=64, k1=9, N2=32, k2=7, NC=10
// Workspace offsets (in floats)
#define OFF_D1   0          // 512   : d^-1/2 for adj1 rows (4*128)
#define OFF_S1   512        // 8192  : s1[p][n] = sum_k tw1[p,n,k]*rp1[k]
#define OFF_T1   8704       // 576   : T1[p][k] = sum_n tw1[p,n,k]
#define OFF_T    9280       // 32768 : t[g][n][q] = sum_m adj[g,n,m]*s1[q,m]
#define OFF_A2   42048      // 16384 : anorm2[g][p][q]
#define OFF_PART 58432      // 1024  : partial sums [b][c][fh]
#define OFF_AN1  59456      // 65536 : anorm1[g][n][m]
#define OFF_A    131072     // 16777216 : region A (x2, then h2)
#define OFF_B    16908288   // 16777216 : region B (y+z, then v)
#define OFF_Z    17956864   // z = OFF_B + 1048576

// ---------------- prep ----------------
__global__ __launch_bounds__(256) void p1_kernel(const float* __restrict__ adj,
    const float* __restrict__ tw1, const float* __restrict__ rp1, float* __restrict__ ws) {
  int idx = blockIdx.x * 256 + threadIdx.x;
  if (idx < 512) {                       // d1: row degrees of adj+I, clipped, ^-1/2
    int g = idx >> 7, n = idx & 127;
    const float* row = adj + (g * 128 + n) * 128;
    float s = 1.0f;                      // self loop
    for (int m = 0; m < 128; ++m) s += row[m];
    ws[OFF_D1 + idx] = 1.0f / sqrtf(fmaxf(s, 1.0f));
  } else if (idx < 8704) {               // s1[p][n]
    int r = idx - 512; int p = r >> 7, n = r & 127;
    const float* tp = tw1 + (p * 128 + n) * 9;
    float s = 0.f;
#pragma unroll
    for (int k = 0; k < 9; ++k) s += tp[k] * rp1[k];
    ws[OFF_S1 + r] = s;
  } else if (idx < 9280) {               // T1[p][k]
    int r = idx - 8704; int p = r / 9, k = r - p * 9;
    float s = 0.f;
    for (int n = 0; n < 128; ++n) s += tw1[(p * 128 + n) * 9 + k];
    ws[OFF_T1 + r] = s;
  }
}

__global__ __launch_bounds__(256) void p1b_kernel(const float* __restrict__ adj,
                                                  float* __restrict__ ws) {
  int idx = blockIdx.x * 256 + threadIdx.x;   // 65536 = 4*128*128
  int g = idx >> 14, n = (idx >> 7) & 127, m = idx & 127;
  float v = adj[idx] + (n == m ? 1.0f : 0.0f);
  ws[OFF_AN1 + idx] = ws[OFF_D1 + g * 128 + n] * ws[OFF_D1 + g * 128 + m] * v;
}

__global__ __launch_bounds__(256) void p2_kernel(const float* __restrict__ adj,
                                                 float* __restrict__ ws) {
  int idx = blockIdx.x * 256 + threadIdx.x;   // 32768 = 4*128*64
  int g = idx >> 13, n = (idx >> 6) & 127, q = idx & 63;
  const float* row = adj + (g * 128 + n) * 128;
  const float* s1 = ws + OFF_S1 + q * 128;
  float s = 0.f;
  for (int m = 0; m < 128; ++m) s += row[m] * s1[m];
  ws[OFF_T + idx] = s;
}

__global__ __launch_bounds__(256) void p3_kernel(float* __restrict__ ws) {
  __shared__ float ap[4096];
  __shared__ float d2[64];
  int g = blockIdx.x, t = threadIdx.x;
  for (int i = t; i < 4096; i += 256) {
    int p = i >> 6, q = i & 63;
    const float* s1 = ws + OFF_S1 + p * 128;
    const float* tg = ws + OFF_T + g * 8192 + q;
    float s = 0.f;
    for (int n = 0; n < 128; ++n) s += s1[n] * tg[n * 64];
    ap[i] = s;
  }
  __syncthreads();
  if (t < 64) {
    float s = 1.0f;
    for (int q = 0; q < 64; ++q) s += ap[t * 64 + q];
    d2[t] = 1.0f / sqrtf(fmaxf(s, 1.0f));
  }
  __syncthreads();
  for (int i = t; i < 4096; i += 256) {
    int p = i >> 6, q = i & 63;
    float vv = ap[i] + (p == q ? 1.0f : 0.0f);
    ws[OFF_A2 + g * 4096 + i] = d2[p] * d2[q] * vv;
  }
}

// ---------------- y[b,n,f] = sum_m anorm1[g(f),n,m] * x[b,m,f] ----------------
__global__ __launch_bounds__(256) void k1_y(const float* __restrict__ x,
                                            float* __restrict__ ws) {
  int b = blockIdx.x, ny = blockIdx.y, fh = blockIdx.z;
  int f = fh * 256 + threadIdx.x;
  int g = f >> 7;
  const float* A = ws + OFF_AN1 + g * 16384;
  const float* xb = x + b * 65536;
  int n0 = ny * 4;
  const float* A0 = A + (n0 + 0) * 128;
  const float* A1 = A + (n0 + 1) * 128;
  const float* A2r = A + (n0 + 2) * 128;
  const float* A3 = A + (n0 + 3) * 128;
  float a0 = 0, a1 = 0, a2 = 0, a3 = 0;
#pragma unroll 4
  for (int m = 0; m < 128; ++m) {
    float xv = xb[m * 512 + f];
    a0 += A0[m] * xv; a1 += A1[m] * xv; a2 += A2r[m] * xv; a3 += A3[m] * xv;
  }
  float* y = ws + OFF_B;
  y[(b * 128 + n0 + 0) * 512 + f] = a0;
  y[(b * 128 + n0 + 1) * 512 + f] = a1;
  y[(b * 128 + n0 + 2) * 512 + f] = a2;
  y[(b * 128 + n0 + 3) * 512 + f] = a3;
}

// ---------------- z[b,(p,k),f] = sum_n tw1[p,n,k] * y[b,n,f] ----------------
__global__ __launch_bounds__(256) void k2_z(const float* __restrict__ tw1,
                                            float* __restrict__ ws) {
  __shared__ __align__(16) float Ys[128 * 64];
  __shared__ __align__(16) float TWs[64 * 64];
  int b = blockIdx.x, rt = blockIdx.y, ft = blockIdx.z;
  int t = threadIdx.x;
  const float* y = ws + OFF_B;
  for (int i = t; i < 8192; i += 256) {
    int m = i >> 6, fi = i & 63;
    Ys[i] = y[(b * 128 + m) * 512 + ft * 64 + fi];
  }
  int w = t >> 6, lane = t & 63;
  int tf = lane & 15, rh = lane >> 4;
  int r0 = w * 16 + rh * 4;
  int f0 = tf * 4;
  float acc[4][4] = {};
  for (int mh = 0; mh < 2; ++mh) {
    __syncthreads();
    for (int i = t; i < 4096; i += 256) {
      int ml = i >> 6, rr = i & 63;
      int r = rt * 64 + rr;
      int p = r / 9, k = r - p * 9;
      TWs[i] = tw1[(p * 128 + (mh * 64 + ml)) * 9 + k];
    }
    __syncthreads();
#pragma unroll 4
    for (int ml = 0; ml < 64; ++ml) {
      int m = mh * 64 + ml;
      float4 tw4 = *(const float4*)&TWs[ml * 64 + r0];
      float4 yv = *(const float4*)&Ys[m * 64 + f0];
      float tr[4] = {tw4.x, tw4.y, tw4.z, tw4.w};
      float yj[4] = {yv.x, yv.y, yv.z, yv.w};
#pragma unroll
      for (int ri = 0; ri < 4; ++ri)
#pragma unroll
        for (int j = 0; j < 4; ++j) acc[ri][j] += tr[ri] * yj[j];
    }
  }
  float* z = ws + OFF_Z + ((size_t)b * 576 + rt * 64) * 512 + ft * 64;
#pragma unroll
  for (int ri = 0; ri < 4; ++ri) {
    float4 st = make_float4(acc[ri][0], acc[ri][1], acc[ri][2], acc[ri][3]);
    *(float4*)&z[(r0 + ri) * 512 + f0] = st;
  }
}

// -------- x2[b,c,p,f] = relu( sum_k W1[g(f+k-4),c]*z[b,(p,k),f+k-4] + b1[c]*Tsum + tb1[p] )
__global__ __launch_bounds__(256) void k4_combine(const float* __restrict__ W1,
    const float* __restrict__ b1, const float* __restrict__ tb1, float* __restrict__ ws) {
  __shared__ float W1s[128];
  __shared__ float b1s[32];
  __shared__ float T1s[9];
  int b = blockIdx.x, p = blockIdx.y, t = threadIdx.x;
  if (t < 128) W1s[t] = W1[t];
  if (t < 32) b1s[t] = b1[t];
  if (t >= 128 && t < 137) T1s[t - 128] = ws[OFF_T1 + p * 9 + (t - 128)];
  float tb = tb1[p];
  __syncthreads();
  const float* z = ws + OFF_Z + (size_t)b * 294912 + (size_t)p * 4608;
  float* x2 = ws + OFF_A;
  for (int pass = 0; pass < 2; ++pass) {
    int f = pass * 256 + t;
    float zv[9]; int gk[9];
    float tsum = 0.f;
#pragma unroll
    for (int k = 0; k < 9; ++k) {
      int fp = f + k - 4;
      bool val = (fp >= 0 && fp < 512);
      zv[k] = val ? z[k * 512 + fp] : 0.0f;
      gk[k] = val ? (fp >> 7) : 0;
      tsum += val ? T1s[k] : 0.0f;
    }
    float acc[32];
#pragma unroll
    for (int c = 0; c < 32; ++c) acc[c] = b1s[c] * tsum + tb;
#pragma unroll
    for (int k = 0; k < 9; ++k) {
      const float4* Wc = (const float4*)&W1s[gk[k] * 32];
      float zk = zv[k];
#pragma unroll
      for (int c4 = 0; c4 < 8; ++c4) {
        float4 wv = Wc[c4];
        acc[c4 * 4 + 0] += wv.x * zk;
        acc[c4 * 4 + 1] += wv.y * zk;
        acc[c4 * 4 + 2] += wv.z * zk;
        acc[c4 * 4 + 3] += wv.w * zk;
      }
    }
#pragma unroll
    for (int c = 0; c < 32; ++c)
      x2[((b * 32 + c) * 64 + p) * 512 + f] = fmaxf(acc[c], 0.0f);
  }
}

// ---------------- v[b,o,n,f] = sum_c W2[g(f),o,c] * x2[b,c,n,f] ----------------
__global__ __launch_bounds__(256) void k5a_v(const float* __restrict__ W2,
                                             float* __restrict__ ws) {
  __shared__ __align__(16) float W2s[4096];
  int b = blockIdx.x, n = blockIdx.y, t = threadIdx.x;
  for (int i = t; i < 4096; i += 256) W2s[i] = W2[i];
  __syncthreads();
  const float* x2 = ws + OFF_A;
  float* v = ws + OFF_B;
  for (int pass = 0; pass < 2; ++pass) {
    int f = pass * 256 + t;
    int g = f >> 7;
    float xc[32];
#pragma unroll
    for (int c = 0; c < 32; ++c) xc[c] = x2[((b * 32 + c) * 64 + n) * 512 + f];
    const float4* Wg4 = (const float4*)(W2s + g * 1024);
#pragma unroll 2
    for (int o = 0; o < 32; ++o) {
      float s = 0.f;
#pragma unroll
      for (int c4 = 0; c4 < 8; ++c4) {
        float4 wv = Wg4[o * 8 + c4];
        s += wv.x * xc[c4 * 4] + wv.y * xc[c4 * 4 + 1] + wv.z * xc[c4 * 4 + 2] + wv.w * xc[c4 * 4 + 3];
      }
      v[((b * 32 + o) * 64 + n) * 512 + f] = s;
    }
  }
}

// ---------------- h2[b,o,n,f] = sum_m anorm2[g(f),n,m]*v[b,o,m,f] + b2[o] ----------------
__global__ __launch_bounds__(256) void k5b_h2(const float* __restrict__ b2,
                                              float* __restrict__ ws) {
  __shared__ __align__(16) float A2t[64 * 68];   // [m][n] padded
  __shared__ __align__(16) float Vs[64 * 128];   // [m][f]
  int b = blockIdx.x, o = blockIdx.y, t = threadIdx.x;
  int w = t >> 6, lane = t & 63;
  int fgrp = lane & 31, ngrh = lane >> 5;
  int n0 = w * 16 + ngrh * 8;
  int f0 = fgrp * 4;
  float bias = b2[o];
  const float* vg = ws + OFF_B;
  float* h2 = ws + OFF_A;
  const float* a2 = ws + OFF_A2;
  for (int g = 0; g < 4; ++g) {
    __syncthreads();
    for (int i = t; i < 4096; i += 256) {
      int m = i & 63, n = i >> 6;
      A2t[m * 68 + n] = a2[g * 4096 + n * 64 + m];
    }
    for (int i = t; i < 8192; i += 256) {
      int m = i >> 7, fi = i & 127;
      Vs[i] = vg[((b * 32 + o) * 64 + m) * 512 + g * 128 + fi];
    }
    __syncthreads();
    float acc[8][4] = {};
#pragma unroll 4
    for (int m = 0; m < 64; ++m) {
      float4 a0 = *(const float4*)&A2t[m * 68 + n0];
      float4 a1 = *(const float4*)&A2t[m * 68 + n0 + 4];
      float4 vv = *(const float4*)&Vs[m * 128 + f0];
      float an[8] = {a0.x, a0.y, a0.z, a0.w, a1.x, a1.y, a1.z, a1.w};
      float vj[4] = {vv.x, vv.y, vv.z, vv.w};
#pragma unroll
      for (int i = 0; i < 8; ++i)
#pragma unroll
        for (int j = 0; j < 4; ++j) acc[i][j] += an[i] * vj[j];
    }
#pragma unroll
    for (int i = 0; i < 8; ++i) {
      int n = n0 + i;
      float4 st = make_float4(acc[i][0] + bias, acc[i][1] + bias,
                              acc[i][2] + bias, acc[i][3] + bias);
      *(float4*)&h2[((b * 32 + o) * 64 + n) * 512 + g * 128 + f0] = st;
    }
  }
}

// ------- conv2 (implicit GEMM over (n,k)) + tb2 + relu + partial mean -------
__global__ __launch_bounds__(256) void k6_conv2(const float* __restrict__ tw2,
    const float* __restrict__ tb2, float* __restrict__ ws) {
  __shared__ __align__(16) float h2s[32 * 264];   // [n][262 pad 264], f' = fh*256 + ii - 3
  __shared__ __align__(16) float tw2s[7168];      // [n][k][q]
  __shared__ float red[256];
  int b = blockIdx.x, c = blockIdx.y, fh = blockIdx.z, t = threadIdx.x;
  int w = t >> 6, lane = t & 63;
  int q0 = w * 8, fl = lane * 4;
  const float* h2 = ws + OFF_A;
  float acc[8][4] = {};
  for (int nh = 0; nh < 2; ++nh) {
    __syncthreads();
    for (int i = t; i < 8384; i += 256) {     // 32*262
      int n = i / 262, ii = i - n * 262;
      int fp = fh * 256 + ii - 3;
      float vv = 0.f;
      if (fp >= 0 && fp < 512) vv = h2[((b * 32 + c) * 64 + nh * 32 + n) * 512 + fp];
      h2s[n * 264 + ii] = vv;
    }
    for (int i = t; i < 7168; i += 256) {     // 32*7*32
      int n = i / 224, r = i - n * 224;
      int k = r >> 5, q = r & 31;
      tw2s[(n * 7 + k) * 32 + q] = tw2[(q * 64 + nh * 32 + n) * 7 + k];
    }
    __syncthreads();
    for (int n = 0; n < 32; ++n) {
      const float* hr = &h2s[n * 264 + fl];
      float4 ha = *(const float4*)hr;
      float4 hb = *(const float4*)(hr + 4);
      float2 hc = *(const float2*)(hr + 8);
      float hv[10] = {ha.x, ha.y, ha.z, ha.w, hb.x, hb.y, hb.z, hb.w, hc.x, hc.y};
#pragma unroll
      for (int k = 0; k < 7; ++k) {
        float4 ta = *(const float4*)&tw2s[(n * 7 + k) * 32 + q0];
        float4 tb = *(const float4*)&tw2s[(n * 7 + k) * 32 + q0 + 4];
        float tq[8] = {ta.x, ta.y, ta.z, ta.w, tb.x, tb.y, tb.z, tb.w};
#pragma unroll
        for (int j = 0; j < 4; ++j) {
          float hh = hv[k + j];
#pragma unroll
          for (int qi = 0; qi < 8; ++qi) acc[qi][j] += tq[qi] * hh;
        }
      }
    }
  }
  float s = 0.f;
#pragma unroll
  for (int qi = 0; qi < 8; ++qi) {
    float tbv = tb2[q0 + qi];
#pragma unroll
    for (int j = 0; j < 4; ++j) s += fmaxf(acc[qi][j] + tbv, 0.0f);
  }
  red[t] = s;
  __syncthreads();
  for (int off = 128; off > 0; off >>= 1) {
    if (t < off) red[t] += red[t + off];
    __syncthreads();
  }
  if (t == 0) ws[OFF_PART + (b * 32 + c) * 2 + fh] = red[0];
}

// ---------------- final: feat mean + linear ----------------
__global__ __launch_bounds__(256) void k7_final(const float* __restrict__ Wout,
    const float* __restrict__ bout, const float* __restrict__ ws, float* __restrict__ out) {
  __shared__ float feat[512];
  int t = threadIdx.x;
  for (int i = t; i < 512; i += 256)
    feat[i] = (ws[OFF_PART + i * 2] + ws[OFF_PART + i * 2 + 1]) * (1.0f / 16384.0f);
  __syncthreads();
  if (t < 160) {
    int bb = t / 10, j = t - bb * 10;
    float acc = bout[j];
    for (int c = 0; c < 32; ++c) acc += feat[bb * 32 + c] * Wout[j * 32 + c];
    out[t] = acc;
  }
}

extern "C" void kernel_launch(void* const* d_in, const int* in_sizes, int n_in,
                              void* d_out, int out_size, void* d_ws, size_t ws_size,
                              hipStream_t stream) {
  const float* x    = (const float*)d_in[0];
  const float* adj  = (const float*)d_in[1];
  const float* W1   = (const float*)d_in[2];
  const float* b1   = (const float*)d_in[3];
  const float* tw1  = (const float*)d_in[4];
  const float* tb1  = (const float*)d_in[5];
  const float* rp1  = (const float*)d_in[6];
  const float* W2   = (const float*)d_in[7];
  const float* b2   = (const float*)d_in[8];
  const float* tw2  = (const float*)d_in[9];
  const float* tb2  = (const float*)d_in[10];
  // d_in[11] = rp2 : unused (second pooled adjacency is dead in the reference)
  const float* Wout = (const float*)d_in[12];
  const float* bout = (const float*)d_in[13];
  float* out = (float*)d_out;
  float* ws = (float*)d_ws;

  p1_kernel <<<37, 256, 0, stream>>>(adj, tw1, rp1, ws);
  p1b_kernel<<<256, 256, 0, stream>>>(adj, ws);
  p2_kernel <<<128, 256, 0, stream>>>(adj, ws);
  p3_kernel <<<4, 256, 0, stream>>>(ws);
  k1_y      <<<dim3(16, 32, 2), 256, 0, stream>>>(x, ws);
  k2_z      <<<dim3(16, 9, 8), 256, 0, stream>>>(tw1, ws);
  k4_combine<<<dim3(16, 64), 256, 0, stream>>>(W1, b1, tb1, ws);
  k5a_v     <<<dim3(16, 64), 256, 0, stream>>>(W2, ws);
  k5b_h2    <<<dim3(16, 32), 256, 0, stream>>>(b2, ws);
  k6_conv2  <<<dim3(16, 32, 2), 256, 0, stream>>>(tw2, tb2, ws);
  k7_final  <<<1, 256, 0, stream>>>(Wout, bout, ws, out);
}

// Round 2
// 308.534 us; speedup vs baseline: 1.1796x; 1.1796x over previous
//
#include <hip/hip_runtime.h>
#include <math.h>

// Problem sizes: B=16, Cin=1, CH=32, N0=128, F=512, G=4, N1=64, k1=9, N2=32, k2=7, NC=10
// Workspace offsets (in floats)
#define OFF_D1   0          // 512   : d^-1/2 for adj1 rows (4*128)
#define OFF_S1   512        // 8192  : s1[p][n] = sum_k tw1[p,n,k]*rp1[k]
#define OFF_T1   8704       // 576   : T1[p][k] = sum_n tw1[p,n,k]
#define OFF_TWP  9280       // 14336 : packed tw2: TWP[(n*7+k)*32+q] = tw2[(q*64+n)*7+k]
#define OFF_T    23616      // 32768 : t[g][n][q] = sum_m adj[g,n,m]*s1[q,m]
#define OFF_A2   56384      // 16384 : anorm2[g][p][q]
#define OFF_PART 72768      // 1024  : partial sums [b][c][fh]
#define OFF_AN1  73792      // 65536 : anorm1[g][n][m]
#define OFF_A    139328     // 16777216 : region A (v)
#define OFF_B    16916544   // 16777216 : region B (y+z, then h2)
#define OFF_Z    17965120   // z = OFF_B + 1048576

// ---------------- prep ----------------
__global__ __launch_bounds__(256) void p1_kernel(const float* __restrict__ adj,
    const float* __restrict__ tw1, const float* __restrict__ rp1,
    const float* __restrict__ tw2, float* __restrict__ ws) {
  int idx = blockIdx.x * 256 + threadIdx.x;
  if (idx < 512) {                       // d1: row degrees of adj+I, clipped, ^-1/2
    int g = idx >> 7, n = idx & 127;
    const float* row = adj + (g * 128 + n) * 128;
    float s = 1.0f;                      // self loop
    for (int m = 0; m < 128; ++m) s += row[m];
    ws[OFF_D1 + idx] = 1.0f / sqrtf(fmaxf(s, 1.0f));
  } else if (idx < 8704) {               // s1[p][n]
    int r = idx - 512; int p = r >> 7, n = r & 127;
    const float* tp = tw1 + (p * 128 + n) * 9;
    float s = 0.f;
#pragma unroll
    for (int k = 0; k < 9; ++k) s += tp[k] * rp1[k];
    ws[OFF_S1 + r] = s;
  } else if (idx < 9280) {               // T1[p][k]
    int r = idx - 8704; int p = r / 9, k = r - p * 9;
    float s = 0.f;
    for (int n = 0; n < 128; ++n) s += tw1[(p * 128 + n) * 9 + k];
    ws[OFF_T1 + r] = s;
  } else if (idx < 23616) {              // TWP packed tw2 [n][k][q]
    int r = idx - 9280;
    int q = r & 31, nk = r >> 5;
    int k = nk % 7, n = nk / 7;
    ws[OFF_TWP + r] = tw2[(q * 64 + n) * 7 + k];
  }
}

__global__ __launch_bounds__(256) void p1b_kernel(const float* __restrict__ adj,
                                                  float* __restrict__ ws) {
  int idx = blockIdx.x * 256 + threadIdx.x;   // 65536 = 4*128*128
  int g = idx >> 14, n = (idx >> 7) & 127, m = idx & 127;
  float v = adj[idx] + (n == m ? 1.0f : 0.0f);
  ws[OFF_AN1 + idx] = ws[OFF_D1 + g * 128 + n] * ws[OFF_D1 + g * 128 + m] * v;
}

__global__ __launch_bounds__(256) void p2_kernel(const float* __restrict__ adj,
                                                 float* __restrict__ ws) {
  int idx = blockIdx.x * 256 + threadIdx.x;   // 32768 = 4*128*64
  int g = idx >> 13, n = (idx >> 6) & 127, q = idx & 63;
  const float* row = adj + (g * 128 + n) * 128;
  const float* s1 = ws + OFF_S1 + q * 128;
  float s = 0.f;
  for (int m = 0; m < 128; ++m) s += row[m] * s1[m];
  ws[OFF_T + idx] = s;
}

__global__ __launch_bounds__(256) void p3_kernel(float* __restrict__ ws) {
  __shared__ float ap[4096];
  __shared__ float d2[64];
  int g = blockIdx.x, t = threadIdx.x;
  for (int i = t; i < 4096; i += 256) {
    int p = i >> 6, q = i & 63;
    const float* s1 = ws + OFF_S1 + p * 128;
    const float* tg = ws + OFF_T + g * 8192 + q;
    float s = 0.f;
    for (int n = 0; n < 128; ++n) s += s1[n] * tg[n * 64];
    ap[i] = s;
  }
  __syncthreads();
  if (t < 64) {
    float s = 1.0f;
    for (int q = 0; q < 64; ++q) s += ap[t * 64 + q];
    d2[t] = 1.0f / sqrtf(fmaxf(s, 1.0f));
  }
  __syncthreads();
  for (int i = t; i < 4096; i += 256) {
    int p = i >> 6, q = i & 63;
    float vv = ap[i] + (p == q ? 1.0f : 0.0f);
    ws[OFF_A2 + g * 4096 + i] = d2[p] * d2[q] * vv;
  }
}

// ---------------- y[b,n,f] = sum_m anorm1[g(f),n,m] * x[b,m,f] ----------------
__global__ __launch_bounds__(256) void k1_y(const float* __restrict__ x,
                                            float* __restrict__ ws) {
  int b = blockIdx.x, ny = blockIdx.y, fh = blockIdx.z;
  int f = fh * 256 + threadIdx.x;
  int g = f >> 7;
  const float* A = ws + OFF_AN1 + g * 16384;
  const float* xb = x + b * 65536;
  int n0 = ny * 4;
  const float* A0 = A + (n0 + 0) * 128;
  const float* A1 = A + (n0 + 1) * 128;
  const float* A2r = A + (n0 + 2) * 128;
  const float* A3 = A + (n0 + 3) * 128;
  float a0 = 0, a1 = 0, a2 = 0, a3 = 0;
#pragma unroll 4
  for (int m = 0; m < 128; ++m) {
    float xv = xb[m * 512 + f];
    a0 += A0[m] * xv; a1 += A1[m] * xv; a2 += A2r[m] * xv; a3 += A3[m] * xv;
  }
  float* y = ws + OFF_B;
  y[(b * 128 + n0 + 0) * 512 + f] = a0;
  y[(b * 128 + n0 + 1) * 512 + f] = a1;
  y[(b * 128 + n0 + 2) * 512 + f] = a2;
  y[(b * 128 + n0 + 3) * 512 + f] = a3;
}

// ---------------- z[b,(p,k),f] = sum_n tw1[p,n,k] * y[b,n,f] ----------------
__global__ __launch_bounds__(256) void k2_z(const float* __restrict__ tw1,
                                            float* __restrict__ ws) {
  __shared__ __align__(16) float Ys[128 * 64];
  __shared__ __align__(16) float TWs[64 * 64];
  int b = blockIdx.x, rt = blockIdx.y, ft = blockIdx.z;
  int t = threadIdx.x;
  const float* y = ws + OFF_B;
  for (int i = t; i < 8192; i += 256) {
    int m = i >> 6, fi = i & 63;
    Ys[i] = y[(b * 128 + m) * 512 + ft * 64 + fi];
  }
  int w = t >> 6, lane = t & 63;
  int tf = lane & 15, rh = lane >> 4;
  int r0 = w * 16 + rh * 4;
  int f0 = tf * 4;
  float acc[4][4] = {};
  for (int mh = 0; mh < 2; ++mh) {
    __syncthreads();
    for (int i = t; i < 4096; i += 256) {
      int ml = i >> 6, rr = i & 63;
      int r = rt * 64 + rr;
      int p = r / 9, k = r - p * 9;
      TWs[i] = tw1[(p * 128 + (mh * 64 + ml)) * 9 + k];
    }
    __syncthreads();
#pragma unroll 4
    for (int ml = 0; ml < 64; ++ml) {
      int m = mh * 64 + ml;
      float4 tw4 = *(const float4*)&TWs[ml * 64 + r0];
      float4 yv = *(const float4*)&Ys[m * 64 + f0];
      float tr[4] = {tw4.x, tw4.y, tw4.z, tw4.w};
      float yj[4] = {yv.x, yv.y, yv.z, yv.w};
#pragma unroll
      for (int ri = 0; ri < 4; ++ri)
#pragma unroll
        for (int j = 0; j < 4; ++j) acc[ri][j] += tr[ri] * yj[j];
    }
  }
  float* z = ws + OFF_Z + ((size_t)b * 576 + rt * 64) * 512 + ft * 64;
#pragma unroll
  for (int ri = 0; ri < 4; ++ri) {
    float4 st = make_float4(acc[ri][0], acc[ri][1], acc[ri][2], acc[ri][3]);
    *(float4*)&z[(r0 + ri) * 512 + f0] = st;
  }
}

// -------- fused: x2[c,f] = relu(sum_k W1*z + b1*Tsum + tb1) ; v[o,f] = sum_c W2*x2
__global__ __launch_bounds__(256) void k45_fused(const float* __restrict__ W1,
    const float* __restrict__ b1, const float* __restrict__ tb1,
    const float* __restrict__ W2, float* __restrict__ ws) {
  __shared__ float W1s[128];
  __shared__ float b1s[32];
  __shared__ float T1s[9];
  __shared__ __align__(16) float W2s[4096];
  int b = blockIdx.x, p = blockIdx.y, t = threadIdx.x;
  for (int i = t; i < 4096; i += 256) W2s[i] = W2[i];
  if (t < 128) W1s[t] = W1[t];
  else if (t < 160) b1s[t - 128] = b1[t - 128];
  else if (t < 169) T1s[t - 160] = ws[OFF_T1 + p * 9 + (t - 160)];
  float tb = tb1[p];
  __syncthreads();
  const float* z = ws + OFF_Z + (size_t)b * 294912 + (size_t)p * 4608;
  float* v = ws + OFF_A;
  for (int pass = 0; pass < 2; ++pass) {
    int f = pass * 256 + t;
    float zv[9]; int gk[9];
    float tsum = 0.f;
#pragma unroll
    for (int k = 0; k < 9; ++k) {
      int fp = f + k - 4;
      bool val = (fp >= 0 && fp < 512);
      zv[k] = val ? z[k * 512 + fp] : 0.0f;
      gk[k] = val ? (fp >> 7) : 0;
      tsum += val ? T1s[k] : 0.0f;
    }
    float acc[32];
#pragma unroll
    for (int c = 0; c < 32; ++c) acc[c] = b1s[c] * tsum + tb;
#pragma unroll
    for (int k = 0; k < 9; ++k) {
      const float4* Wc = (const float4*)&W1s[gk[k] * 32];
      float zk = zv[k];
#pragma unroll
      for (int c4 = 0; c4 < 8; ++c4) {
        float4 wv = Wc[c4];
        acc[c4 * 4 + 0] += wv.x * zk;
        acc[c4 * 4 + 1] += wv.y * zk;
        acc[c4 * 4 + 2] += wv.z * zk;
        acc[c4 * 4 + 3] += wv.w * zk;
      }
    }
#pragma unroll
    for (int c = 0; c < 32; ++c) acc[c] = fmaxf(acc[c], 0.0f);   // x2 in regs
    int g = f >> 7;
    const float4* Wg4 = (const float4*)(W2s + g * 1024);
#pragma unroll 2
    for (int o = 0; o < 32; ++o) {
      float s = 0.f;
#pragma unroll
      for (int c4 = 0; c4 < 8; ++c4) {
        float4 wv = Wg4[o * 8 + c4];
        s += wv.x * acc[c4 * 4] + wv.y * acc[c4 * 4 + 1] + wv.z * acc[c4 * 4 + 2] + wv.w * acc[c4 * 4 + 3];
      }
      v[((b * 32 + o) * 64 + p) * 512 + f] = s;
    }
  }
}

// ---------------- h2[b,o,n,f] = sum_m anorm2[g(f),n,m]*v[b,o,m,f] + b2[o] ----------------
__global__ __launch_bounds__(256) void k5b_h2(const float* __restrict__ b2,
                                              float* __restrict__ ws) {
  __shared__ __align__(16) float A2t[64 * 68];   // [m][n] padded
  __shared__ __align__(16) float Vs[64 * 128];   // [m][f]
  int b = blockIdx.x, o = blockIdx.y, t = threadIdx.x;
  int w = t >> 6, lane = t & 63;
  int fgrp = lane & 31, ngrh = lane >> 5;
  int n0 = w * 16 + ngrh * 8;
  int f0 = fgrp * 4;
  float bias = b2[o];
  const float* vg = ws + OFF_A;
  float* h2 = ws + OFF_B;
  const float* a2 = ws + OFF_A2;
  for (int g = 0; g < 4; ++g) {
    __syncthreads();
    for (int i = t; i < 4096; i += 256) {
      int m = i & 63, n = i >> 6;
      A2t[m * 68 + n] = a2[g * 4096 + n * 64 + m];
    }
    for (int i = t; i < 8192; i += 256) {
      int m = i >> 7, fi = i & 127;
      Vs[i] = vg[((b * 32 + o) * 64 + m) * 512 + g * 128 + fi];
    }
    __syncthreads();
    float acc[8][4] = {};
#pragma unroll 4
    for (int m = 0; m < 64; ++m) {
      float4 a0 = *(const float4*)&A2t[m * 68 + n0];
      float4 a1 = *(const float4*)&A2t[m * 68 + n0 + 4];
      float4 vv = *(const float4*)&Vs[m * 128 + f0];
      float an[8] = {a0.x, a0.y, a0.z, a0.w, a1.x, a1.y, a1.z, a1.w};
      float vj[4] = {vv.x, vv.y, vv.z, vv.w};
#pragma unroll
      for (int i = 0; i < 8; ++i)
#pragma unroll
        for (int j = 0; j < 4; ++j) acc[i][j] += an[i] * vj[j];
    }
#pragma unroll
    for (int i = 0; i < 8; ++i) {
      int n = n0 + i;
      float4 st = make_float4(acc[i][0] + bias, acc[i][1] + bias,
                              acc[i][2] + bias, acc[i][3] + bias);
      *(float4*)&h2[((b * 32 + o) * 64 + n) * 512 + g * 128 + f0] = st;
    }
  }
}

// ------- conv2 (implicit GEMM over (n,k)) + tb2 + relu + partial mean -------
// Weights come from packed TWP in global memory via wave-uniform (scalar) loads;
// LDS holds only the h-operand -> ~3 LDS reads per 224 FMAs per wave.
__global__ __launch_bounds__(256) void k6_conv2(const float* __restrict__ tb2,
                                                float* __restrict__ ws) {
  __shared__ __align__(16) float h2s[32 * 264];   // [n][262 pad 264], f' = fh*256 + ii - 3
  __shared__ float red[256];
  int b = blockIdx.x, c = blockIdx.y, fh = blockIdx.z, t = threadIdx.x;
  int w = __builtin_amdgcn_readfirstlane(t >> 6);   // wave-uniform
  int lane = t & 63;
  int q0 = w * 8, fl = lane * 4;
  const float* h2 = ws + OFF_B;
  const float* twp = ws + OFF_TWP;
  float acc[8][4] = {};
  for (int nh = 0; nh < 2; ++nh) {
    __syncthreads();
    for (int i = t; i < 8384; i += 256) {     // 32*262
      int n = i / 262, ii = i - n * 262;
      int fp = fh * 256 + ii - 3;
      float vv = 0.f;
      if (fp >= 0 && fp < 512) vv = h2[((b * 32 + c) * 64 + nh * 32 + n) * 512 + fp];
      h2s[n * 264 + ii] = vv;
    }
    __syncthreads();
#pragma unroll 2
    for (int n = 0; n < 32; ++n) {
      const float* hr = &h2s[n * 264 + fl];
      float4 ha = *(const float4*)hr;
      float4 hb = *(const float4*)(hr + 4);
      float2 hc = *(const float2*)(hr + 8);
      float hv[10] = {ha.x, ha.y, ha.z, ha.w, hb.x, hb.y, hb.z, hb.w, hc.x, hc.y};
      const float* tn = twp + ((nh * 32 + n) * 7) * 32 + q0;   // uniform address
#pragma unroll
      for (int k = 0; k < 7; ++k) {
        float4 ta = *(const float4*)(tn + k * 32);
        float4 tb4 = *(const float4*)(tn + k * 32 + 4);
        float tq[8] = {ta.x, ta.y, ta.z, ta.w, tb4.x, tb4.y, tb4.z, tb4.w};
#pragma unroll
        for (int j = 0; j < 4; ++j) {
          float hh = hv[k + j];
#pragma unroll
          for (int qi = 0; qi < 8; ++qi) acc[qi][j] += tq[qi] * hh;
        }
      }
    }
  }
  float s = 0.f;
#pragma unroll
  for (int qi = 0; qi < 8; ++qi) {
    float tbv = tb2[q0 + qi];
#pragma unroll
    for (int j = 0; j < 4; ++j) s += fmaxf(acc[qi][j] + tbv, 0.0f);
  }
  red[t] = s;
  __syncthreads();
  for (int off = 128; off > 0; off >>= 1) {
    if (t < off) red[t] += red[t + off];
    __syncthreads();
  }
  if (t == 0) ws[OFF_PART + (b * 32 + c) * 2 + fh] = red[0];
}

// ---------------- final: feat mean + linear ----------------
__global__ __launch_bounds__(256) void k7_final(const float* __restrict__ Wout,
    const float* __restrict__ bout, const float* __restrict__ ws, float* __restrict__ out) {
  __shared__ float feat[512];
  int t = threadIdx.x;
  for (int i = t; i < 512; i += 256)
    feat[i] = (ws[OFF_PART + i * 2] + ws[OFF_PART + i * 2 + 1]) * (1.0f / 16384.0f);
  __syncthreads();
  if (t < 160) {
    int bb = t / 10, j = t - bb * 10;
    float acc = bout[j];
    for (int c = 0; c < 32; ++c) acc += feat[bb * 32 + c] * Wout[j * 32 + c];
    out[t] = acc;
  }
}

extern "C" void kernel_launch(void* const* d_in, const int* in_sizes, int n_in,
                              void* d_out, int out_size, void* d_ws, size_t ws_size,
                              hipStream_t stream) {
  const float* x    = (const float*)d_in[0];
  const float* adj  = (const float*)d_in[1];
  const float* W1   = (const float*)d_in[2];
  const float* b1   = (const float*)d_in[3];
  const float* tw1  = (const float*)d_in[4];
  const float* tb1  = (const float*)d_in[5];
  const float* rp1  = (const float*)d_in[6];
  const float* W2   = (const float*)d_in[7];
  const float* b2   = (const float*)d_in[8];
  const float* tw2  = (const float*)d_in[9];
  const float* tb2  = (const float*)d_in[10];
  // d_in[11] = rp2 : unused (second pooled adjacency is dead in the reference)
  const float* Wout = (const float*)d_in[12];
  const float* bout = (const float*)d_in[13];
  float* out = (float*)d_out;
  float* ws = (float*)d_ws;

  p1_kernel <<<93, 256, 0, stream>>>(adj, tw1, rp1, tw2, ws);
  p1b_kernel<<<256, 256, 0, stream>>>(adj, ws);
  p2_kernel <<<128, 256, 0, stream>>>(adj, ws);
  p3_kernel <<<4, 256, 0, stream>>>(ws);
  k1_y      <<<dim3(16, 32, 2), 256, 0, stream>>>(x, ws);
  k2_z      <<<dim3(16, 9, 8), 256, 0, stream>>>(tw1, ws);
  k45_fused <<<dim3(16, 64), 256, 0, stream>>>(W1, b1, tb1, W2, ws);
  k5b_h2    <<<dim3(16, 32), 256, 0, stream>>>(b2, ws);
  k6_conv2  <<<dim3(16, 32, 2), 256, 0, stream>>>(tb2, ws);
  k7_final  <<<1, 256, 0, stream>>>(Wout, bout, ws, out);
}

// Round 3
// 219.633 us; speedup vs baseline: 1.6570x; 1.4048x over previous
//
#include <hip/hip_runtime.h>
#include <math.h>

// Problem sizes: B=16, Cin=1, CH=32, N0=128, F=512, G=4, N1=64, k1=9, N2=32, k2=7, NC=10
// Workspace offsets (in float units)
#define OFF_D1   0          // 512   : d^-1/2 for adj1 rows (4*128)
#define OFF_S1   512        // 8192  : s1[p][n] = sum_k tw1[p,n,k]*rp1[k]
#define OFF_T1   8704       // 576   : T1[p][k] = sum_n tw1[p,n,k]
#define OFF_TWB  9280       // 7168 float-slots = 14336 ushort : bf16 tw2 packed [q][k][n]
#define OFF_T    16448      // 32768 : t[g][n][q] = sum_m adj[g,n,m]*s1[q,m]
#define OFF_A2   49216      // 16384 : anorm2[g][p][q]
#define OFF_PART 65600      // 512   : partial sums [b][c]
#define OFF_AN1  66112      // 65536 : anorm1[g][n][m]
#define OFF_A    131648     // 8388608 float-slots: v as bf16 [b,o,n,f] (16.7M ushort)
#define OFF_B    8520256    // region B: y fp32 (1048576), then reused by h2T bf16 (8388608 slots)
#define OFF_Z    9568832    // z fp32 (4718592)

typedef short bf16x8 __attribute__((ext_vector_type(8)));
typedef float f32x4 __attribute__((ext_vector_type(4)));

static __device__ __forceinline__ unsigned short f2bf(float x) {
  union { float f; unsigned u; } v; v.f = x;
  unsigned r = v.u + 0x7FFF + ((v.u >> 16) & 1);   // RNE
  return (unsigned short)(r >> 16);
}
static __device__ __forceinline__ float bf2f(unsigned short h) {
  union { unsigned u; float f; } v; v.u = ((unsigned)h) << 16;
  return v.f;
}

// ---------------- prep ----------------
__global__ __launch_bounds__(256) void p1_kernel(const float* __restrict__ adj,
    const float* __restrict__ tw1, const float* __restrict__ rp1,
    const float* __restrict__ tw2, float* __restrict__ ws) {
  int idx = blockIdx.x * 256 + threadIdx.x;
  if (idx < 512) {                       // d1: row degrees of adj+I, clipped, ^-1/2
    int g = idx >> 7, n = idx & 127;
    const float* row = adj + (g * 128 + n) * 128;
    float s = 1.0f;                      // self loop
    for (int m = 0; m < 128; ++m) s += row[m];
    ws[OFF_D1 + idx] = 1.0f / sqrtf(fmaxf(s, 1.0f));
  } else if (idx < 8704) {               // s1[p][n]
    int r = idx - 512; int p = r >> 7, n = r & 127;
    const float* tp = tw1 + (p * 128 + n) * 9;
    float s = 0.f;
#pragma unroll
    for (int k = 0; k < 9; ++k) s += tp[k] * rp1[k];
    ws[OFF_S1 + r] = s;
  } else if (idx < 9280) {               // T1[p][k]
    int r = idx - 8704; int p = r / 9, k = r - p * 9;
    float s = 0.f;
    for (int n = 0; n < 128; ++n) s += tw1[(p * 128 + n) * 9 + k];
    ws[OFF_T1 + r] = s;
  } else if (idx < 23616) {              // twB bf16 [q][k][n]: q*448 + k*64 + n
    int r = idx - 9280;
    int q = r / 448, rem = r - q * 448;
    int k = rem >> 6, n = rem & 63;
    ((unsigned short*)(ws + OFF_TWB))[r] = f2bf(tw2[(q * 64 + n) * 7 + k]);
  }
}

__global__ __launch_bounds__(256) void p1b_kernel(const float* __restrict__ adj,
                                                  float* __restrict__ ws) {
  int idx = blockIdx.x * 256 + threadIdx.x;   // 65536 = 4*128*128
  int g = idx >> 14, n = (idx >> 7) & 127, m = idx & 127;
  float v = adj[idx] + (n == m ? 1.0f : 0.0f);
  ws[OFF_AN1 + idx] = ws[OFF_D1 + g * 128 + n] * ws[OFF_D1 + g * 128 + m] * v;
}

__global__ __launch_bounds__(256) void p2_kernel(const float* __restrict__ adj,
                                                 float* __restrict__ ws) {
  int idx = blockIdx.x * 256 + threadIdx.x;   // 32768 = 4*128*64
  int g = idx >> 13, n = (idx >> 6) & 127, q = idx & 63;
  const float* row = adj + (g * 128 + n) * 128;
  const float* s1 = ws + OFF_S1 + q * 128;
  float s = 0.f;
  for (int m = 0; m < 128; ++m) s += row[m] * s1[m];
  ws[OFF_T + idx] = s;
}

__global__ __launch_bounds__(256) void p3_kernel(float* __restrict__ ws) {
  __shared__ float ap[4096];
  __shared__ float d2[64];
  int g = blockIdx.x, t = threadIdx.x;
  for (int i = t; i < 4096; i += 256) {
    int p = i >> 6, q = i & 63;
    const float* s1 = ws + OFF_S1 + p * 128;
    const float* tg = ws + OFF_T + g * 8192 + q;
    float s = 0.f;
    for (int n = 0; n < 128; ++n) s += s1[n] * tg[n * 64];
    ap[i] = s;
  }
  __syncthreads();
  if (t < 64) {
    float s = 1.0f;
    for (int q = 0; q < 64; ++q) s += ap[t * 64 + q];
    d2[t] = 1.0f / sqrtf(fmaxf(s, 1.0f));
  }
  __syncthreads();
  for (int i = t; i < 4096; i += 256) {
    int p = i >> 6, q = i & 63;
    float vv = ap[i] + (p == q ? 1.0f : 0.0f);
    ws[OFF_A2 + g * 4096 + i] = d2[p] * d2[q] * vv;
  }
}

// ---------------- y[b,n,f] = sum_m anorm1[g(f),n,m] * x[b,m,f] ----------------
__global__ __launch_bounds__(256) void k1_y(const float* __restrict__ x,
                                            float* __restrict__ ws) {
  int b = blockIdx.x, ny = blockIdx.y, fh = blockIdx.z;
  int f = fh * 256 + threadIdx.x;
  int g = f >> 7;
  const float* A = ws + OFF_AN1 + g * 16384;
  const float* xb = x + b * 65536;
  int n0 = ny * 4;
  const float* A0 = A + (n0 + 0) * 128;
  const float* A1 = A + (n0 + 1) * 128;
  const float* A2r = A + (n0 + 2) * 128;
  const float* A3 = A + (n0 + 3) * 128;
  float a0 = 0, a1 = 0, a2 = 0, a3 = 0;
#pragma unroll 4
  for (int m = 0; m < 128; ++m) {
    float xv = xb[m * 512 + f];
    a0 += A0[m] * xv; a1 += A1[m] * xv; a2 += A2r[m] * xv; a3 += A3[m] * xv;
  }
  float* y = ws + OFF_B;
  y[(b * 128 + n0 + 0) * 512 + f] = a0;
  y[(b * 128 + n0 + 1) * 512 + f] = a1;
  y[(b * 128 + n0 + 2) * 512 + f] = a2;
  y[(b * 128 + n0 + 3) * 512 + f] = a3;
}

// ---------------- z[b,(p,k),f] = sum_n tw1[p,n,k] * y[b,n,f] ----------------
__global__ __launch_bounds__(256) void k2_z(const float* __restrict__ tw1,
                                            float* __restrict__ ws) {
  __shared__ __align__(16) float Ys[128 * 64];
  __shared__ __align__(16) float TWs[64 * 64];
  int b = blockIdx.x, rt = blockIdx.y, ft = blockIdx.z;
  int t = threadIdx.x;
  const float* y = ws + OFF_B;
  for (int i = t; i < 8192; i += 256) {
    int m = i >> 6, fi = i & 63;
    Ys[i] = y[(b * 128 + m) * 512 + ft * 64 + fi];
  }
  int w = t >> 6, lane = t & 63;
  int tf = lane & 15, rh = lane >> 4;
  int r0 = w * 16 + rh * 4;
  int f0 = tf * 4;
  float acc[4][4] = {};
  for (int mh = 0; mh < 2; ++mh) {
    __syncthreads();
    for (int i = t; i < 4096; i += 256) {
      int ml = i >> 6, rr = i & 63;
      int r = rt * 64 + rr;
      int p = r / 9, k = r - p * 9;
      TWs[i] = tw1[(p * 128 + (mh * 64 + ml)) * 9 + k];
    }
    __syncthreads();
#pragma unroll 4
    for (int ml = 0; ml < 64; ++ml) {
      int m = mh * 64 + ml;
      float4 tw4 = *(const float4*)&TWs[ml * 64 + r0];
      float4 yv = *(const float4*)&Ys[m * 64 + f0];
      float tr[4] = {tw4.x, tw4.y, tw4.z, tw4.w};
      float yj[4] = {yv.x, yv.y, yv.z, yv.w};
#pragma unroll
      for (int ri = 0; ri < 4; ++ri)
#pragma unroll
        for (int j = 0; j < 4; ++j) acc[ri][j] += tr[ri] * yj[j];
    }
  }
  float* z = ws + OFF_Z + ((size_t)b * 576 + rt * 64) * 512 + ft * 64;
#pragma unroll
  for (int ri = 0; ri < 4; ++ri) {
    float4 st = make_float4(acc[ri][0], acc[ri][1], acc[ri][2], acc[ri][3]);
    *(float4*)&z[(r0 + ri) * 512 + f0] = st;
  }
}

// -------- fused: x2[c,f] = relu(sum_k W1*z + b1*Tsum + tb1) ; v[o,f] = sum_c W2*x2 (bf16 out)
__global__ __launch_bounds__(256) void k45_fused(const float* __restrict__ W1,
    const float* __restrict__ b1, const float* __restrict__ tb1,
    const float* __restrict__ W2, float* __restrict__ ws) {
  __shared__ float W1s[128];
  __shared__ float b1s[32];
  __shared__ float T1s[9];
  __shared__ __align__(16) float W2s[4096];
  int b = blockIdx.x, p = blockIdx.y, t = threadIdx.x;
  for (int i = t; i < 4096; i += 256) W2s[i] = W2[i];
  if (t < 128) W1s[t] = W1[t];
  else if (t < 160) b1s[t - 128] = b1[t - 128];
  else if (t < 169) T1s[t - 160] = ws[OFF_T1 + p * 9 + (t - 160)];
  float tb = tb1[p];
  __syncthreads();
  const float* z = ws + OFF_Z + (size_t)b * 294912 + (size_t)p * 4608;
  unsigned short* vb = (unsigned short*)(ws + OFF_A);
  for (int pass = 0; pass < 2; ++pass) {
    int f = pass * 256 + t;
    float zv[9]; int gk[9];
    float tsum = 0.f;
#pragma unroll
    for (int k = 0; k < 9; ++k) {
      int fp = f + k - 4;
      bool val = (fp >= 0 && fp < 512);
      zv[k] = val ? z[k * 512 + fp] : 0.0f;
      gk[k] = val ? (fp >> 7) : 0;
      tsum += val ? T1s[k] : 0.0f;
    }
    float acc[32];
#pragma unroll
    for (int c = 0; c < 32; ++c) acc[c] = b1s[c] * tsum + tb;
#pragma unroll
    for (int k = 0; k < 9; ++k) {
      const float4* Wc = (const float4*)&W1s[gk[k] * 32];
      float zk = zv[k];
#pragma unroll
      for (int c4 = 0; c4 < 8; ++c4) {
        float4 wv = Wc[c4];
        acc[c4 * 4 + 0] += wv.x * zk;
        acc[c4 * 4 + 1] += wv.y * zk;
        acc[c4 * 4 + 2] += wv.z * zk;
        acc[c4 * 4 + 3] += wv.w * zk;
      }
    }
#pragma unroll
    for (int c = 0; c < 32; ++c) acc[c] = fmaxf(acc[c], 0.0f);   // x2 in regs
    int g = f >> 7;
    const float4* Wg4 = (const float4*)(W2s + g * 1024);
#pragma unroll 2
    for (int o = 0; o < 32; ++o) {
      float s = 0.f;
#pragma unroll
      for (int c4 = 0; c4 < 8; ++c4) {
        float4 wv = Wg4[o * 8 + c4];
        s += wv.x * acc[c4 * 4] + wv.y * acc[c4 * 4 + 1] + wv.z * acc[c4 * 4 + 2] + wv.w * acc[c4 * 4 + 3];
      }
      vb[((b * 32 + o) * 64 + p) * 512 + f] = f2bf(s);
    }
  }
}

// ---- h2T[b,o,f,n] (bf16) = sum_m anorm2[g(f),n,m]*v[b,o,m,f] + b2[o], stored transposed ----
__global__ __launch_bounds__(256) void k5b_h2(const float* __restrict__ b2,
                                              float* __restrict__ ws) {
  __shared__ __align__(16) float A2t[64 * 68];   // [m][n] padded
  __shared__ __align__(16) float Vs[64 * 128];   // [m][f]
  int b = blockIdx.x, o = blockIdx.y, t = threadIdx.x;
  int w = t >> 6, lane = t & 63;
  int fgrp = lane & 31, ngrh = lane >> 5;
  int n0 = w * 16 + ngrh * 8;
  int f0 = fgrp * 4;
  float bias = b2[o];
  const unsigned short* vb = (const unsigned short*)(ws + OFF_A);
  unsigned short* h2T = (unsigned short*)(ws + OFF_B);
  const float* a2 = ws + OFF_A2;
  for (int g = 0; g < 4; ++g) {
    __syncthreads();
    for (int i = t; i < 4096; i += 256) {
      int m = i & 63, n = i >> 6;
      A2t[m * 68 + n] = a2[g * 4096 + n * 64 + m];
    }
    for (int i = t; i < 8192; i += 256) {
      int m = i >> 7, fi = i & 127;
      Vs[i] = bf2f(vb[((b * 32 + o) * 64 + m) * 512 + g * 128 + fi]);
    }
    __syncthreads();
    float acc[8][4] = {};
#pragma unroll 4
    for (int m = 0; m < 64; ++m) {
      float4 a0 = *(const float4*)&A2t[m * 68 + n0];
      float4 a1 = *(const float4*)&A2t[m * 68 + n0 + 4];
      float4 vv = *(const float4*)&Vs[m * 128 + f0];
      float an[8] = {a0.x, a0.y, a0.z, a0.w, a1.x, a1.y, a1.z, a1.w};
      float vj[4] = {vv.x, vv.y, vv.z, vv.w};
#pragma unroll
      for (int i = 0; i < 8; ++i)
#pragma unroll
        for (int j = 0; j < 4; ++j) acc[i][j] += an[i] * vj[j];
    }
    // transposed bf16 store: for each j (f), pack 8 consecutive n
#pragma unroll
    for (int j = 0; j < 4; ++j) {
      unsigned short hs[8];
#pragma unroll
      for (int i = 0; i < 8; ++i) hs[i] = f2bf(acc[i][j] + bias);
      int f = g * 128 + f0 + j;
      *(uint4*)&h2T[(((size_t)(b * 32 + o) * 512 + f) * 64) + n0] = *(uint4*)hs;
    }
  }
}

// ------- conv2 via bf16 MFMA implicit GEMM + tb2 + relu + mean partial -------
// Per (b,c): out[32q,512f] = TW[32q, K=448] * H[K,512f], K=(ktap*64+n),
// H[K][f] = h2[n][f+ktap-3]  (read from h2T[f'][n], rows r=f'+3 in LDS, XOR-swizzled)
#define L_H2T 0        // 518 rows * 128B = 66304
#define L_TWB 66304    // 32 q * 912B = 29184
#define L_RED 95488    // 8 floats
__global__ __launch_bounds__(512) void k6_conv2(const float* __restrict__ tb2,
                                                float* __restrict__ ws) {
  __shared__ __align__(16) unsigned char sm[95520];
  int b = blockIdx.x, c = blockIdx.y, t = threadIdx.x;
  const uint4* h2T4 = (const uint4*)((const unsigned short*)(ws + OFF_B) +
                                     (size_t)(b * 32 + c) * 32768);
  // stage h2sT rows r=0..517 (f' = r-3), swizzle: 16B slot ^= (r&7)
  for (int ci = t; ci < 4144; ci += 512) {
    int r = ci >> 3, slot = ci & 7;
    int f = r - 3;
    uint4 val = make_uint4(0u, 0u, 0u, 0u);
    if (f >= 0 && f < 512) val = h2T4[f * 8 + slot];
    *(uint4*)(sm + r * 128 + ((slot ^ (r & 7)) << 4)) = val;
  }
  // stage twB bf16 [q][k][n], padded pitch 912B per q
  const uint4* twg = (const uint4*)(ws + OFF_TWB);
  for (int ci = t; ci < 1792; ci += 512) {
    int q = ci / 56, rem = ci - q * 56;
    *(uint4*)(sm + L_TWB + q * 912 + rem * 16) = twg[ci];
  }
  __syncthreads();
  int w = t >> 6, l = t & 63;
  int ll = l & 15, lhi = l >> 4;
  // A fragments in registers: A[Mt][ks], lane: q=Mt*16+ll, k-elems = ks*32+lhi*8+j
  bf16x8 A[2][14];
#pragma unroll
  for (int Mt = 0; Mt < 2; ++Mt)
#pragma unroll
    for (int ks = 0; ks < 14; ++ks) {
      int q = Mt * 16 + ll;
      A[Mt][ks] = *(const bf16x8*)(sm + L_TWB + q * 912 + (ks >> 1) * 128 +
                                   (ks & 1) * 64 + lhi * 16);
    }
  f32x4 zero = {0.f, 0.f, 0.f, 0.f};
  f32x4 acc[2][4];
#pragma unroll
  for (int Mt = 0; Mt < 2; ++Mt)
#pragma unroll
    for (int Nt = 0; Nt < 4; ++Nt) acc[Mt][Nt] = zero;
  int rbase = w * 64 + ll;          // f-col base + in-tile col
#pragma unroll
  for (int ks = 0; ks < 14; ++ks) {
    int rb = rbase + (ks >> 1);     // row = f + ktap
    int x = (((ks & 1) * 4 + lhi) ^ (rb & 7)) << 4;
#pragma unroll
    for (int Nt = 0; Nt < 4; ++Nt) {
      bf16x8 Bf = *(const bf16x8*)(sm + (rb + Nt * 16) * 128 + x);
      acc[0][Nt] = __builtin_amdgcn_mfma_f32_16x16x32_bf16(A[0][ks], Bf, acc[0][Nt], 0, 0, 0);
      acc[1][Nt] = __builtin_amdgcn_mfma_f32_16x16x32_bf16(A[1][ks], Bf, acc[1][Nt], 0, 0, 0);
    }
  }
  // epilogue: q = Mt*16 + lhi*4 + i ; relu(val + tb2[q]) summed for the mean
  float tbv[8];
#pragma unroll
  for (int Mt = 0; Mt < 2; ++Mt)
#pragma unroll
    for (int i = 0; i < 4; ++i) tbv[Mt * 4 + i] = tb2[Mt * 16 + lhi * 4 + i];
  float s = 0.f;
#pragma unroll
  for (int Mt = 0; Mt < 2; ++Mt)
#pragma unroll
    for (int Nt = 0; Nt < 4; ++Nt)
#pragma unroll
      for (int i = 0; i < 4; ++i)
        s += fmaxf(acc[Mt][Nt][i] + tbv[Mt * 4 + i], 0.0f);
#pragma unroll
  for (int off = 32; off > 0; off >>= 1) s += __shfl_down(s, off, 64);
  float* red = (float*)(sm + L_RED);
  if (l == 0) red[w] = s;
  __syncthreads();
  if (t == 0) {
    float tot = 0.f;
    for (int i = 0; i < 8; ++i) tot += red[i];
    ws[OFF_PART + b * 32 + c] = tot;
  }
}

// ---------------- final: feat mean + linear ----------------
__global__ __launch_bounds__(256) void k7_final(const float* __restrict__ Wout,
    const float* __restrict__ bout, const float* __restrict__ ws, float* __restrict__ out) {
  __shared__ float feat[512];
  int t = threadIdx.x;
  for (int i = t; i < 512; i += 256)
    feat[i] = ws[OFF_PART + i] * (1.0f / 16384.0f);
  __syncthreads();
  if (t < 160) {
    int bb = t / 10, j = t - bb * 10;
    float acc = bout[j];
    for (int c = 0; c < 32; ++c) acc += feat[bb * 32 + c] * Wout[j * 32 + c];
    out[t] = acc;
  }
}

extern "C" void kernel_launch(void* const* d_in, const int* in_sizes, int n_in,
                              void* d_out, int out_size, void* d_ws, size_t ws_size,
                              hipStream_t stream) {
  const float* x    = (const float*)d_in[0];
  const float* adj  = (const float*)d_in[1];
  const float* W1   = (const float*)d_in[2];
  const float* b1   = (const float*)d_in[3];
  const float* tw1  = (const float*)d_in[4];
  const float* tb1  = (const float*)d_in[5];
  const float* rp1  = (const float*)d_in[6];
  const float* W2   = (const float*)d_in[7];
  const float* b2   = (const float*)d_in[8];
  const float* tw2  = (const float*)d_in[9];
  const float* tb2  = (const float*)d_in[10];
  // d_in[11] = rp2 : unused (second pooled adjacency is dead in the reference)
  const float* Wout = (const float*)d_in[12];
  const float* bout = (const float*)d_in[13];
  float* out = (float*)d_out;
  float* ws = (float*)d_ws;

  p1_kernel <<<93, 256, 0, stream>>>(adj, tw1, rp1, tw2, ws);
  p1b_kernel<<<256, 256, 0, stream>>>(adj, ws);
  p2_kernel <<<128, 256, 0, stream>>>(adj, ws);
  p3_kernel <<<4, 256, 0, stream>>>(ws);
  k1_y      <<<dim3(16, 32, 2), 256, 0, stream>>>(x, ws);
  k2_z      <<<dim3(16, 9, 8), 256, 0, stream>>>(tw1, ws);
  k45_fused <<<dim3(16, 64), 256, 0, stream>>>(W1, b1, tb1, W2, ws);
  k5b_h2    <<<dim3(16, 32), 256, 0, stream>>>(b2, ws);
  k6_conv2  <<<dim3(16, 32), 512, 0, stream>>>(tb2, ws);
  k7_final  <<<1, 256, 0, stream>>>(Wout, bout, ws, out);
}

// Round 5
// 196.740 us; speedup vs baseline: 1.8498x; 1.1164x over previous
//
#include <hip/hip_runtime.h>
#include <math.h>

// Problem sizes: B=16, Cin=1, CH=32, N0=128, F=512, G=4, N1=64, k1=9, N2=32, k2=7, NC=10
// Workspace offsets (float units)
#define OFF_D1   0          // 512
#define OFF_S1   512        // 8192  : s1[p][n]
#define OFF_T1   8704       // 576   : T1[p][k]
#define OFF_TWB  9280       // 7168 slots = 14336 ushort : bf16 tw2 packed [q][k][n]
#define OFF_T    16448      // 32768 : t[g][n][q]
#define OFF_A2   49216      // 16384 : anorm2[g][n][m] fp32 (kept for debug, unused)
#define OFF_A2H  65600      // 8192 slots = 16384 ushort : bf16 hi of anorm2 [g][n][m]
#define OFF_A2L  73792      // 8192 slots : bf16 lo residual [g][n][m]
#define OFF_PART 81984      // 512   : partial sums [b][c]
#define OFF_AN1  82496      // 65536 : anorm1[g][n][m]
#define OFF_A    148032     // 8388608 slots : v bf16 plain [b,o][p][f]
#define OFF_B    8536640    // region B: y fp32 (1048576), then h2T bf16 [b,o][f][n]
#define OFF_Z    16925248   // 4718592 : z fp32

typedef short bf16x8 __attribute__((ext_vector_type(8)));
typedef short short4v __attribute__((ext_vector_type(4)));
typedef float f32x4 __attribute__((ext_vector_type(4)));

static __device__ __forceinline__ unsigned short f2bf(float x) {
  union { float f; unsigned u; } v; v.f = x;
  unsigned r = v.u + 0x7FFF + ((v.u >> 16) & 1);   // RNE
  return (unsigned short)(r >> 16);
}
static __device__ __forceinline__ float bf2f(unsigned short h) {
  union { unsigned u; float f; } v; v.u = ((unsigned)h) << 16;
  return v.f;
}

// ---------------- prep ----------------
__global__ __launch_bounds__(256) void p1_kernel(const float* __restrict__ adj,
    const float* __restrict__ tw1, const float* __restrict__ rp1,
    const float* __restrict__ tw2, float* __restrict__ ws) {
  int idx = blockIdx.x * 256 + threadIdx.x;
  if (idx < 512) {
    int g = idx >> 7, n = idx & 127;
    const float* row = adj + (g * 128 + n) * 128;
    float s = 1.0f;
    for (int m = 0; m < 128; ++m) s += row[m];
    ws[OFF_D1 + idx] = 1.0f / sqrtf(fmaxf(s, 1.0f));
  } else if (idx < 8704) {
    int r = idx - 512; int p = r >> 7, n = r & 127;
    const float* tp = tw1 + (p * 128 + n) * 9;
    float s = 0.f;
#pragma unroll
    for (int k = 0; k < 9; ++k) s += tp[k] * rp1[k];
    ws[OFF_S1 + r] = s;
  } else if (idx < 9280) {
    int r = idx - 8704; int p = r / 9, k = r - p * 9;
    float s = 0.f;
    for (int n = 0; n < 128; ++n) s += tw1[(p * 128 + n) * 9 + k];
    ws[OFF_T1 + r] = s;
  } else if (idx < 23616) {              // twB bf16 [q][k][n]: q*448 + k*64 + n
    int r = idx - 9280;
    int q = r / 448, rem = r - q * 448;
    int k = rem >> 6, n = rem & 63;
    ((unsigned short*)(ws + OFF_TWB))[r] = f2bf(tw2[(q * 64 + n) * 7 + k]);
  }
}

__global__ __launch_bounds__(256) void p1b_kernel(const float* __restrict__ adj,
                                                  float* __restrict__ ws) {
  int idx = blockIdx.x * 256 + threadIdx.x;   // 65536
  int g = idx >> 14, n = (idx >> 7) & 127, m = idx & 127;
  float v = adj[idx] + (n == m ? 1.0f : 0.0f);
  ws[OFF_AN1 + idx] = ws[OFF_D1 + g * 128 + n] * ws[OFF_D1 + g * 128 + m] * v;
}

__global__ __launch_bounds__(256) void p2_kernel(const float* __restrict__ adj,
                                                 float* __restrict__ ws) {
  int idx = blockIdx.x * 256 + threadIdx.x;   // 32768
  int g = idx >> 13, n = (idx >> 6) & 127, q = idx & 63;
  const float* row = adj + (g * 128 + n) * 128;
  const float* s1 = ws + OFF_S1 + q * 128;
  float s = 0.f;
  for (int m = 0; m < 128; ++m) s += row[m] * s1[m];
  ws[OFF_T + idx] = s;
}

__global__ __launch_bounds__(256) void p3_kernel(float* __restrict__ ws) {
  __shared__ float ap[4096];
  __shared__ float d2[64];
  int g = blockIdx.x, t = threadIdx.x;
  for (int i = t; i < 4096; i += 256) {
    int p = i >> 6, q = i & 63;
    const float* s1 = ws + OFF_S1 + p * 128;
    const float* tg = ws + OFF_T + g * 8192 + q;
    float s = 0.f;
    for (int n = 0; n < 128; ++n) s += s1[n] * tg[n * 64];
    ap[i] = s;
  }
  __syncthreads();
  if (t < 64) {
    float s = 1.0f;
    for (int q = 0; q < 64; ++q) s += ap[t * 64 + q];
    d2[t] = 1.0f / sqrtf(fmaxf(s, 1.0f));
  }
  __syncthreads();
  for (int i = t; i < 4096; i += 256) {
    int p = i >> 6, q = i & 63;
    float vv = ap[i] + (p == q ? 1.0f : 0.0f);
    float fullv = d2[p] * d2[q] * vv;
    ws[OFF_A2 + g * 4096 + i] = fullv;
    unsigned short hi = f2bf(fullv);
    float lo = fullv - bf2f(hi);
    ((unsigned short*)(ws + OFF_A2H))[g * 4096 + i] = hi;
    ((unsigned short*)(ws + OFF_A2L))[g * 4096 + i] = f2bf(lo);
  }
}

// ---------------- y[b,n,f] = sum_m anorm1[g(f),n,m] * x[b,m,f] ----------------
__global__ __launch_bounds__(256) void k1_y(const float* __restrict__ x,
                                            float* __restrict__ ws) {
  int b = blockIdx.x, ny = blockIdx.y, fh = blockIdx.z;
  int f = fh * 256 + threadIdx.x;
  int g = f >> 7;
  const float* A = ws + OFF_AN1 + g * 16384;
  const float* xb = x + b * 65536;
  int n0 = ny * 4;
  const float* A0 = A + (n0 + 0) * 128;
  const float* A1 = A + (n0 + 1) * 128;
  const float* A2r = A + (n0 + 2) * 128;
  const float* A3 = A + (n0 + 3) * 128;
  float a0 = 0, a1 = 0, a2 = 0, a3 = 0;
#pragma unroll 4
  for (int m = 0; m < 128; ++m) {
    float xv = xb[m * 512 + f];
    a0 += A0[m] * xv; a1 += A1[m] * xv; a2 += A2r[m] * xv; a3 += A3[m] * xv;
  }
  float* y = ws + OFF_B;
  y[(b * 128 + n0 + 0) * 512 + f] = a0;
  y[(b * 128 + n0 + 1) * 512 + f] = a1;
  y[(b * 128 + n0 + 2) * 512 + f] = a2;
  y[(b * 128 + n0 + 3) * 512 + f] = a3;
}

// ---------------- z[b,(p,k),f] = sum_n tw1[p,n,k] * y[b,n,f] ----------------
__global__ __launch_bounds__(256) void k2_z(const float* __restrict__ tw1,
                                            float* __restrict__ ws) {
  __shared__ __align__(16) float Ys[128 * 64];
  __shared__ __align__(16) float TWs[64 * 64];
  int b = blockIdx.x, rt = blockIdx.y, ft = blockIdx.z;
  int t = threadIdx.x;
  const float* y = ws + OFF_B;
  for (int i = t; i < 8192; i += 256) {
    int m = i >> 6, fi = i & 63;
    Ys[i] = y[(b * 128 + m) * 512 + ft * 64 + fi];
  }
  int w = t >> 6, lane = t & 63;
  int tf = lane & 15, rh = lane >> 4;
  int r0 = w * 16 + rh * 4;
  int f0 = tf * 4;
  float acc[4][4] = {};
  for (int mh = 0; mh < 2; ++mh) {
    __syncthreads();
    for (int i = t; i < 4096; i += 256) {
      int ml = i >> 6, rr = i & 63;
      int r = rt * 64 + rr;
      int p = r / 9, k = r - p * 9;
      TWs[i] = tw1[(p * 128 + (mh * 64 + ml)) * 9 + k];
    }
    __syncthreads();
#pragma unroll 4
    for (int ml = 0; ml < 64; ++ml) {
      int m = mh * 64 + ml;
      float4 tw4 = *(const float4*)&TWs[ml * 64 + r0];
      float4 yv = *(const float4*)&Ys[m * 64 + f0];
      float tr[4] = {tw4.x, tw4.y, tw4.z, tw4.w};
      float yj[4] = {yv.x, yv.y, yv.z, yv.w};
#pragma unroll
      for (int ri = 0; ri < 4; ++ri)
#pragma unroll
        for (int j = 0; j < 4; ++j) acc[ri][j] += tr[ri] * yj[j];
    }
  }
  float* z = ws + OFF_Z + ((size_t)b * 576 + rt * 64) * 512 + ft * 64;
#pragma unroll
  for (int ri = 0; ri < 4; ++ri) {
    float4 st = make_float4(acc[ri][0], acc[ri][1], acc[ri][2], acc[ri][3]);
    *(float4*)&z[(r0 + ri) * 512 + f0] = st;
  }
}

// -------- fused: x2[c,f] = relu(sum_k W1*z + b1*Tsum + tb1) ; v[o,f] = sum_c W2*x2
// v written bf16, plain layout [b,o][p][f] (contiguous stores)
__global__ __launch_bounds__(256) void k45_fused(const float* __restrict__ W1,
    const float* __restrict__ b1, const float* __restrict__ tb1,
    const float* __restrict__ W2, float* __restrict__ ws) {
  __shared__ float W1s[128];
  __shared__ float b1s[32];
  __shared__ float T1s[9];
  __shared__ __align__(16) float W2s[4096];
  int b = blockIdx.x, p = blockIdx.y, t = threadIdx.x;
  for (int i = t; i < 4096; i += 256) W2s[i] = W2[i];
  if (t < 128) W1s[t] = W1[t];
  else if (t < 160) b1s[t - 128] = b1[t - 128];
  else if (t < 169) T1s[t - 160] = ws[OFF_T1 + p * 9 + (t - 160)];
  float tb = tb1[p];
  __syncthreads();
  const float* z = ws + OFF_Z + (size_t)b * 294912 + (size_t)p * 4608;
  unsigned short* vb = (unsigned short*)(ws + OFF_A);
  for (int pass = 0; pass < 2; ++pass) {
    int f = pass * 256 + t;
    float zv[9]; int gk[9];
    float tsum = 0.f;
#pragma unroll
    for (int k = 0; k < 9; ++k) {
      int fp = f + k - 4;
      bool val = (fp >= 0 && fp < 512);
      zv[k] = val ? z[k * 512 + fp] : 0.0f;
      gk[k] = val ? (fp >> 7) : 0;
      tsum += val ? T1s[k] : 0.0f;
    }
    float acc[32];
#pragma unroll
    for (int c = 0; c < 32; ++c) acc[c] = b1s[c] * tsum + tb;
#pragma unroll
    for (int k = 0; k < 9; ++k) {
      const float4* Wc = (const float4*)&W1s[gk[k] * 32];
      float zk = zv[k];
#pragma unroll
      for (int c4 = 0; c4 < 8; ++c4) {
        float4 wv = Wc[c4];
        acc[c4 * 4 + 0] += wv.x * zk;
        acc[c4 * 4 + 1] += wv.y * zk;
        acc[c4 * 4 + 2] += wv.z * zk;
        acc[c4 * 4 + 3] += wv.w * zk;
      }
    }
#pragma unroll
    for (int c = 0; c < 32; ++c) acc[c] = fmaxf(acc[c], 0.0f);   // x2 in regs
    int g = f >> 7;
    const float4* Wg4 = (const float4*)(W2s + g * 1024);
#pragma unroll 2
    for (int o = 0; o < 32; ++o) {
      float s = 0.f;
#pragma unroll
      for (int c4 = 0; c4 < 8; ++c4) {
        float4 wv = Wg4[o * 8 + c4];
        s += wv.x * acc[c4 * 4] + wv.y * acc[c4 * 4 + 1] + wv.z * acc[c4 * 4 + 2] + wv.w * acc[c4 * 4 + 3];
      }
      vb[((b * 32 + o) * 64 + p) * 512 + f] = f2bf(s);
    }
  }
}

// ---- h2T[b,o,f,n] (bf16) = sum_m anorm2[g(f),n,m]*v[b,o,m,f] + b2[o] via MFMA ----
// Grid (b, o, g). V transposed into LDS vT[fl][p] with XOR swizzle; B-frags are
// canonical contiguous-K ds_read_b128; A-frags (split-bf16 anorm2) from global.
__global__ __launch_bounds__(256) void k5b_h2(const float* __restrict__ b2,
                                              float* __restrict__ ws) {
  __shared__ __align__(16) unsigned short vT[128 * 64];   // rows fl (128B), swizzled
  int b = blockIdx.x, o = blockIdx.y, g = blockIdx.z, t = threadIdx.x;
  const unsigned short* vbp = (const unsigned short*)(ws + OFF_A) +
                              (size_t)(b * 32 + o) * 32768;
  const uint4* vb4 = (const uint4*)vbp;
  unsigned char* vTw = (unsigned char*)vT;
  // stage V^T: vT[fl][p] = v[p][g*128+fl]; in-row byte ^= (((fl^(fl>>3))&7)<<4)
  for (int i = t; i < 1024; i += 256) {
    int p = i >> 4, u = i & 15;
    uint4 val = vb4[p * 64 + g * 16 + u];
    const unsigned short* hv = (const unsigned short*)&val;
#pragma unroll
    for (int e = 0; e < 8; ++e) {
      int fl = u * 8 + e;
      int addr = fl * 128 + ((p * 2) ^ ((((fl & 7) ^ (fl >> 3)) & 7) << 4));
      *(unsigned short*)(vTw + addr) = hv[e];
    }
  }
  // A fragments direct from global (L2-hot, shared by all blocks of this g)
  int w = t >> 6, l = t & 63, ll = l & 15, lhi = l >> 4;
  const unsigned short* a2h = (const unsigned short*)(ws + OFF_A2H) + g * 4096;
  const unsigned short* a2l = (const unsigned short*)(ws + OFF_A2L) + g * 4096;
  bf16x8 Ah[4][2], Al[4][2];
#pragma unroll
  for (int Mt = 0; Mt < 4; ++Mt)
#pragma unroll
    for (int ks = 0; ks < 2; ++ks) {
      int idx = (Mt * 16 + ll) * 64 + ks * 32 + lhi * 8;
      Ah[Mt][ks] = *(const bf16x8*)(a2h + idx);
      Al[Mt][ks] = *(const bf16x8*)(a2l + idx);
    }
  float bias = b2[o];
  __syncthreads();
  unsigned short* h2T = (unsigned short*)(ws + OFF_B) + (size_t)(b * 32 + o) * 32768;
  const unsigned char* vTr = (const unsigned char*)vT;
#pragma unroll
  for (int fi = 0; fi < 2; ++fi) {
    int fgl = w * 2 + fi;
    int fl = fgl * 16 + ll;
    int swz = (((fl & 7) ^ (fl >> 3)) & 7) << 4;
    bf16x8 Bf[2];
#pragma unroll
    for (int ks = 0; ks < 2; ++ks)
      Bf[ks] = *(const bf16x8*)(vTr + fl * 128 + ((ks * 64 + lhi * 16) ^ swz));
#pragma unroll
    for (int Mt = 0; Mt < 4; ++Mt) {
      f32x4 acc = {0.f, 0.f, 0.f, 0.f};
      acc = __builtin_amdgcn_mfma_f32_16x16x32_bf16(Ah[Mt][0], Bf[0], acc, 0, 0, 0);
      acc = __builtin_amdgcn_mfma_f32_16x16x32_bf16(Al[Mt][0], Bf[0], acc, 0, 0, 0);
      acc = __builtin_amdgcn_mfma_f32_16x16x32_bf16(Ah[Mt][1], Bf[1], acc, 0, 0, 0);
      acc = __builtin_amdgcn_mfma_f32_16x16x32_bf16(Al[Mt][1], Bf[1], acc, 0, 0, 0);
      int f = g * 128 + fgl * 16 + ll;    // D col = lane&15
      int n0 = Mt * 16 + lhi * 4;         // D row = (lane>>4)*4 + reg
      unsigned short hs[4];
#pragma unroll
      for (int i2 = 0; i2 < 4; ++i2) hs[i2] = f2bf(acc[i2] + bias);
      *(short4v*)(h2T + f * 64 + n0) = *(short4v*)hs;
    }
  }
}

// ------- conv2 via bf16 MFMA implicit GEMM + tb2 + relu + mean partial -------
#define L_TWB 66304    // 32 q * 912B = 29184
#define L_RED 95488    // 8 floats
__global__ __launch_bounds__(512) void k6_conv2(const float* __restrict__ tb2,
                                                float* __restrict__ ws) {
  __shared__ __align__(16) unsigned char sm[95520];
  int b = blockIdx.x, c = blockIdx.y, t = threadIdx.x;
  const uint4* h2T4 = (const uint4*)((const unsigned short*)(ws + OFF_B) +
                                     (size_t)(b * 32 + c) * 32768);
  for (int ci = t; ci < 4144; ci += 512) {
    int r = ci >> 3, slot = ci & 7;
    int f = r - 3;
    uint4 val = make_uint4(0u, 0u, 0u, 0u);
    if (f >= 0 && f < 512) val = h2T4[f * 8 + slot];
    *(uint4*)(sm + r * 128 + ((slot ^ (r & 7)) << 4)) = val;
  }
  const uint4* twg = (const uint4*)(ws + OFF_TWB);
  for (int ci = t; ci < 1792; ci += 512) {
    int q = ci / 56, rem = ci - q * 56;
    *(uint4*)(sm + L_TWB + q * 912 + rem * 16) = twg[ci];
  }
  __syncthreads();
  int w = t >> 6, l = t & 63;
  int ll = l & 15, lhi = l >> 4;
  bf16x8 A[2][14];
#pragma unroll
  for (int Mt = 0; Mt < 2; ++Mt)
#pragma unroll
    for (int ks = 0; ks < 14; ++ks) {
      int q = Mt * 16 + ll;
      A[Mt][ks] = *(const bf16x8*)(sm + L_TWB + q * 912 + (ks >> 1) * 128 +
                                   (ks & 1) * 64 + lhi * 16);
    }
  f32x4 zero = {0.f, 0.f, 0.f, 0.f};
  f32x4 acc[2][4];
#pragma unroll
  for (int Mt = 0; Mt < 2; ++Mt)
#pragma unroll
    for (int Nt = 0; Nt < 4; ++Nt) acc[Mt][Nt] = zero;
  int rbase = w * 64 + ll;
#pragma unroll
  for (int ks = 0; ks < 14; ++ks) {
    int rb = rbase + (ks >> 1);
    int x = (((ks & 1) * 4 + lhi) ^ (rb & 7)) << 4;
#pragma unroll
    for (int Nt = 0; Nt < 4; ++Nt) {
      bf16x8 Bf = *(const bf16x8*)(sm + (rb + Nt * 16) * 128 + x);
      acc[0][Nt] = __builtin_amdgcn_mfma_f32_16x16x32_bf16(A[0][ks], Bf, acc[0][Nt], 0, 0, 0);
      acc[1][Nt] = __builtin_amdgcn_mfma_f32_16x16x32_bf16(A[1][ks], Bf, acc[1][Nt], 0, 0, 0);
    }
  }
  float tbv[8];
#pragma unroll
  for (int Mt = 0; Mt < 2; ++Mt)
#pragma unroll
    for (int i = 0; i < 4; ++i) tbv[Mt * 4 + i] = tb2[Mt * 16 + lhi * 4 + i];
  float s = 0.f;
#pragma unroll
  for (int Mt = 0; Mt < 2; ++Mt)
#pragma unroll
    for (int Nt = 0; Nt < 4; ++Nt)
#pragma unroll
      for (int i = 0; i < 4; ++i)
        s += fmaxf(acc[Mt][Nt][i] + tbv[Mt * 4 + i], 0.0f);
#pragma unroll
  for (int off = 32; off > 0; off >>= 1) s += __shfl_down(s, off, 64);
  float* red = (float*)(sm + L_RED);
  if (l == 0) red[w] = s;
  __syncthreads();
  if (t == 0) {
    float tot = 0.f;
    for (int i = 0; i < 8; ++i) tot += red[i];
    ws[OFF_PART + b * 32 + c] = tot;
  }
}

// ---------------- final: feat mean + linear ----------------
__global__ __launch_bounds__(256) void k7_final(const float* __restrict__ Wout,
    const float* __restrict__ bout, const float* __restrict__ ws, float* __restrict__ out) {
  __shared__ float feat[512];
  int t = threadIdx.x;
  for (int i = t; i < 512; i += 256)
    feat[i] = ws[OFF_PART + i] * (1.0f / 16384.0f);
  __syncthreads();
  if (t < 160) {
    int bb = t / 10, j = t - bb * 10;
    float acc = bout[j];
    for (int c = 0; c < 32; ++c) acc += feat[bb * 32 + c] * Wout[j * 32 + c];
    out[t] = acc;
  }
}

extern "C" void kernel_launch(void* const* d_in, const int* in_sizes, int n_in,
                              void* d_out, int out_size, void* d_ws, size_t ws_size,
                              hipStream_t stream) {
  const float* x    = (const float*)d_in[0];
  const float* adj  = (const float*)d_in[1];
  const float* W1   = (const float*)d_in[2];
  const float* b1   = (const float*)d_in[3];
  const float* tw1  = (const float*)d_in[4];
  const float* tb1  = (const float*)d_in[5];
  const float* rp1  = (const float*)d_in[6];
  const float* W2   = (const float*)d_in[7];
  const float* b2   = (const float*)d_in[8];
  const float* tw2  = (const float*)d_in[9];
  const float* tb2  = (const float*)d_in[10];
  // d_in[11] = rp2 : unused (second pooled adjacency is dead in the reference)
  const float* Wout = (const float*)d_in[12];
  const float* bout = (const float*)d_in[13];
  float* out = (float*)d_out;
  float* ws = (float*)d_ws;

  p1_kernel <<<93, 256, 0, stream>>>(adj, tw1, rp1, tw2, ws);
  p1b_kernel<<<256, 256, 0, stream>>>(adj, ws);
  p2_kernel <<<128, 256, 0, stream>>>(adj, ws);
  p3_kernel <<<4, 256, 0, stream>>>(ws);
  k1_y      <<<dim3(16, 32, 2), 256, 0, stream>>>(x, ws);
  k2_z      <<<dim3(16, 9, 8), 256, 0, stream>>>(tw1, ws);
  k45_fused <<<dim3(16, 64), 256, 0, stream>>>(W1, b1, tb1, W2, ws);
  k5b_h2    <<<dim3(16, 32, 4), 256, 0, stream>>>(b2, ws);
  k6_conv2  <<<dim3(16, 32), 512, 0, stream>>>(tb2, ws);
  k7_final  <<<1, 256, 0, stream>>>(Wout, bout, ws, out);
}

// Round 6
// 180.090 us; speedup vs baseline: 2.0209x; 1.0925x over previous
//
#include <hip/hip_runtime.h>
#include <math.h>

// Problem sizes: B=16, Cin=1, CH=32, N0=128, F=512, G=4, N1=64, k1=9, N2=32, k2=7, NC=10
// Workspace offsets (float units)
#define OFF_D1   0          // 512
#define OFF_S1   512        // 8192  : s1[p][n]
#define OFF_T1   8704       // 576   : T1[p][k]
#define OFF_TWB  9280       // 7168 slots = 14336 ushort : bf16 tw2 packed [q][k][n]
#define OFF_T    16448      // 32768 : t[g][n][q]
#define OFF_A2   49216      // 16384 : ap[g][p][q] scratch (pre-normalization)
#define OFF_A2H  65600      // 8192 slots = 16384 ushort : bf16 hi of anorm2 [g][n][m]
#define OFF_A2L  73792      // 8192 slots : bf16 lo residual [g][n][m]
#define OFF_PART 81984      // 512   : partial sums [b][c]
#define OFF_AN1  82496      // 65536 : anorm1[g][n][m]
#define OFF_A    148032     // 8388608 slots : v bf16 plain [b,o][p][f]
#define OFF_B    8536640    // region B: y fp32 (1048576), then h2T bf16 [b,o][f][n]
#define OFF_Z    16925248   // 4718592 : z fp32

typedef short bf16x8 __attribute__((ext_vector_type(8)));
typedef short short4v __attribute__((ext_vector_type(4)));
typedef float f32x4 __attribute__((ext_vector_type(4)));

static __device__ __forceinline__ unsigned short f2bf(float x) {
  union { float f; unsigned u; } v; v.f = x;
  unsigned r = v.u + 0x7FFF + ((v.u >> 16) & 1);   // RNE
  return (unsigned short)(r >> 16);
}
static __device__ __forceinline__ float bf2f(unsigned short h) {
  union { unsigned u; float f; } v; v.u = ((unsigned)h) << 16;
  return v.f;
}

// ---------------- prep ----------------
__global__ __launch_bounds__(256) void p1_kernel(const float* __restrict__ adj,
    const float* __restrict__ tw1, const float* __restrict__ rp1,
    const float* __restrict__ tw2, float* __restrict__ ws) {
  int idx = blockIdx.x * 256 + threadIdx.x;
  if (idx < 512) {
    int g = idx >> 7, n = idx & 127;
    const float* row = adj + (g * 128 + n) * 128;
    float s = 1.0f;
    for (int m = 0; m < 128; ++m) s += row[m];
    ws[OFF_D1 + idx] = 1.0f / sqrtf(fmaxf(s, 1.0f));
  } else if (idx < 8704) {
    int r = idx - 512; int p = r >> 7, n = r & 127;
    const float* tp = tw1 + (p * 128 + n) * 9;
    float s = 0.f;
#pragma unroll
    for (int k = 0; k < 9; ++k) s += tp[k] * rp1[k];
    ws[OFF_S1 + r] = s;
  } else if (idx < 9280) {
    int r = idx - 8704; int p = r / 9, k = r - p * 9;
    float s = 0.f;
    for (int n = 0; n < 128; ++n) s += tw1[(p * 128 + n) * 9 + k];
    ws[OFF_T1 + r] = s;
  } else if (idx < 23616) {              // twB bf16 [q][k][n]: q*448 + k*64 + n
    int r = idx - 9280;
    int q = r / 448, rem = r - q * 448;
    int k = rem >> 6, n = rem & 63;
    ((unsigned short*)(ws + OFF_TWB))[r] = f2bf(tw2[(q * 64 + n) * 7 + k]);
  }
}

__global__ __launch_bounds__(256) void p1b_kernel(const float* __restrict__ adj,
                                                  float* __restrict__ ws) {
  int idx = blockIdx.x * 256 + threadIdx.x;   // 65536
  int g = idx >> 14, n = (idx >> 7) & 127, m = idx & 127;
  float v = adj[idx] + (n == m ? 1.0f : 0.0f);
  ws[OFF_AN1 + idx] = ws[OFF_D1 + g * 128 + n] * ws[OFF_D1 + g * 128 + m] * v;
}

__global__ __launch_bounds__(256) void p2_kernel(const float* __restrict__ adj,
                                                 float* __restrict__ ws) {
  int idx = blockIdx.x * 256 + threadIdx.x;   // 32768
  int g = idx >> 13, n = (idx >> 6) & 127, q = idx & 63;
  const float* row = adj + (g * 128 + n) * 128;
  const float* s1 = ws + OFF_S1 + q * 128;
  float s = 0.f;
  for (int m = 0; m < 128; ++m) s += row[m] * s1[m];
  ws[OFF_T + idx] = s;
}

// ap[g][p][q] = sum_n s1[p][n] * t[g][n][q]  (parallel GEMM part of pooled adj)
__global__ __launch_bounds__(256) void p3a_kernel(float* __restrict__ ws) {
  int g = blockIdx.x, pt = blockIdx.y, t = threadIdx.x;
  int pp = t >> 6, q = t & 63;
  int p = pt * 4 + pp;
  const float* s1 = ws + OFF_S1 + p * 128;
  const float* tg = ws + OFF_T + g * 8192;
  float s = 0.f;
#pragma unroll 4
  for (int n = 0; n < 128; ++n) s += s1[n] * tg[n * 64 + q];
  ws[OFF_A2 + g * 4096 + p * 64 + q] = s;
}

// normalize pooled adjacency, emit split-bf16 (hi + lo residual)
__global__ __launch_bounds__(256) void p3b_kernel(float* __restrict__ ws) {
  __shared__ float ap[4096];
  __shared__ float d2[64];
  int g = blockIdx.x, t = threadIdx.x;
  for (int i = t; i < 4096; i += 256) ap[i] = ws[OFF_A2 + g * 4096 + i];
  __syncthreads();
  if (t < 64) {
    float s = 1.0f;
    for (int q = 0; q < 64; ++q) s += ap[t * 64 + q];
    d2[t] = 1.0f / sqrtf(fmaxf(s, 1.0f));
  }
  __syncthreads();
  for (int i = t; i < 4096; i += 256) {
    int p = i >> 6, q = i & 63;
    float fullv = d2[p] * d2[q] * (ap[i] + (p == q ? 1.0f : 0.0f));
    unsigned short hi = f2bf(fullv);
    float lo = fullv - bf2f(hi);
    ((unsigned short*)(ws + OFF_A2H))[g * 4096 + i] = hi;
    ((unsigned short*)(ws + OFF_A2L))[g * 4096 + i] = f2bf(lo);
  }
}

// ---------------- y[b,n,f] = sum_m anorm1[g(f),n,m] * x[b,m,f] ----------------
__global__ __launch_bounds__(256) void k1_y(const float* __restrict__ x,
                                            float* __restrict__ ws) {
  int b = blockIdx.x, ny = blockIdx.y, fh = blockIdx.z;
  int f = fh * 256 + threadIdx.x;
  int g = f >> 7;
  const float* A = ws + OFF_AN1 + g * 16384;
  const float* xb = x + b * 65536;
  int n0 = ny * 4;
  const float* A0 = A + (n0 + 0) * 128;
  const float* A1 = A + (n0 + 1) * 128;
  const float* A2r = A + (n0 + 2) * 128;
  const float* A3 = A + (n0 + 3) * 128;
  float a0 = 0, a1 = 0, a2 = 0, a3 = 0;
#pragma unroll 4
  for (int m = 0; m < 128; ++m) {
    float xv = xb[m * 512 + f];
    a0 += A0[m] * xv; a1 += A1[m] * xv; a2 += A2r[m] * xv; a3 += A3[m] * xv;
  }
  float* y = ws + OFF_B;
  y[(b * 128 + n0 + 0) * 512 + f] = a0;
  y[(b * 128 + n0 + 1) * 512 + f] = a1;
  y[(b * 128 + n0 + 2) * 512 + f] = a2;
  y[(b * 128 + n0 + 3) * 512 + f] = a3;
}

// ---------------- z[b,(p,k),f] = sum_n tw1[p,n,k] * y[b,n,f] ----------------
__global__ __launch_bounds__(256) void k2_z(const float* __restrict__ tw1,
                                            float* __restrict__ ws) {
  __shared__ __align__(16) float Ys[128 * 64];
  __shared__ __align__(16) float TWs[64 * 64];
  int b = blockIdx.x, rt = blockIdx.y, ft = blockIdx.z;
  int t = threadIdx.x;
  const float* y = ws + OFF_B;
  for (int i = t; i < 8192; i += 256) {
    int m = i >> 6, fi = i & 63;
    Ys[i] = y[(b * 128 + m) * 512 + ft * 64 + fi];
  }
  int w = t >> 6, lane = t & 63;
  int tf = lane & 15, rh = lane >> 4;
  int r0 = w * 16 + rh * 4;
  int f0 = tf * 4;
  float acc[4][4] = {};
  for (int mh = 0; mh < 2; ++mh) {
    __syncthreads();
    for (int i = t; i < 4096; i += 256) {
      int ml = i >> 6, rr = i & 63;
      int r = rt * 64 + rr;
      int p = r / 9, k = r - p * 9;
      TWs[i] = tw1[(p * 128 + (mh * 64 + ml)) * 9 + k];
    }
    __syncthreads();
#pragma unroll 4
    for (int ml = 0; ml < 64; ++ml) {
      int m = mh * 64 + ml;
      float4 tw4 = *(const float4*)&TWs[ml * 64 + r0];
      float4 yv = *(const float4*)&Ys[m * 64 + f0];
      float tr[4] = {tw4.x, tw4.y, tw4.z, tw4.w};
      float yj[4] = {yv.x, yv.y, yv.z, yv.w};
#pragma unroll
      for (int ri = 0; ri < 4; ++ri)
#pragma unroll
        for (int j = 0; j < 4; ++j) acc[ri][j] += tr[ri] * yj[j];
    }
  }
  float* z = ws + OFF_Z + ((size_t)b * 576 + rt * 64) * 512 + ft * 64;
#pragma unroll
  for (int ri = 0; ri < 4; ++ri) {
    float4 st = make_float4(acc[ri][0], acc[ri][1], acc[ri][2], acc[ri][3]);
    *(float4*)&z[(r0 + ri) * 512 + f0] = st;
  }
}

// -------- fused: x2[c,f] = relu(sum_k W1*z + b1*Tsum + tb1) ; v[o,f] = sum_c W2*x2
// v written bf16, plain layout [b,o][p][f] (contiguous stores)
__global__ __launch_bounds__(256) void k45_fused(const float* __restrict__ W1,
    const float* __restrict__ b1, const float* __restrict__ tb1,
    const float* __restrict__ W2, float* __restrict__ ws) {
  __shared__ float W1s[128];
  __shared__ float b1s[32];
  __shared__ float T1s[9];
  __shared__ __align__(16) float W2s[4096];
  int b = blockIdx.x, p = blockIdx.y, t = threadIdx.x;
  for (int i = t; i < 4096; i += 256) W2s[i] = W2[i];
  if (t < 128) W1s[t] = W1[t];
  else if (t < 160) b1s[t - 128] = b1[t - 128];
  else if (t < 169) T1s[t - 160] = ws[OFF_T1 + p * 9 + (t - 160)];
  float tb = tb1[p];
  __syncthreads();
  const float* z = ws + OFF_Z + (size_t)b * 294912 + (size_t)p * 4608;
  unsigned short* vb = (unsigned short*)(ws + OFF_A);
  for (int pass = 0; pass < 2; ++pass) {
    int f = pass * 256 + t;
    float zv[9]; int gk[9];
    float tsum = 0.f;
#pragma unroll
    for (int k = 0; k < 9; ++k) {
      int fp = f + k - 4;
      bool val = (fp >= 0 && fp < 512);
      zv[k] = val ? z[k * 512 + fp] : 0.0f;
      gk[k] = val ? (fp >> 7) : 0;
      tsum += val ? T1s[k] : 0.0f;
    }
    float acc[32];
#pragma unroll
    for (int c = 0; c < 32; ++c) acc[c] = b1s[c] * tsum + tb;
#pragma unroll
    for (int k = 0; k < 9; ++k) {
      const float4* Wc = (const float4*)&W1s[gk[k] * 32];
      float zk = zv[k];
#pragma unroll
      for (int c4 = 0; c4 < 8; ++c4) {
        float4 wv = Wc[c4];
        acc[c4 * 4 + 0] += wv.x * zk;
        acc[c4 * 4 + 1] += wv.y * zk;
        acc[c4 * 4 + 2] += wv.z * zk;
        acc[c4 * 4 + 3] += wv.w * zk;
      }
    }
#pragma unroll
    for (int c = 0; c < 32; ++c) acc[c] = fmaxf(acc[c], 0.0f);   // x2 in regs
    int g = f >> 7;
    const float4* Wg4 = (const float4*)(W2s + g * 1024);
#pragma unroll 2
    for (int o = 0; o < 32; ++o) {
      float s = 0.f;
#pragma unroll
      for (int c4 = 0; c4 < 8; ++c4) {
        float4 wv = Wg4[o * 8 + c4];
        s += wv.x * acc[c4 * 4] + wv.y * acc[c4 * 4 + 1] + wv.z * acc[c4 * 4 + 2] + wv.w * acc[c4 * 4 + 3];
      }
      vb[((b * 32 + o) * 64 + p) * 512 + f] = f2bf(s);
    }
  }
}

// ---- h2T[b,o,f,n] (bf16) = sum_m anorm2[g(f),n,m]*v[b,o,m,f] + b2[o] via MFMA ----
// Grid (b, o, g). V transposed into LDS vT[fl][p] with XOR swizzle; B-frags are
// canonical contiguous-K ds_read_b128; A-frags (split-bf16 anorm2) from global.
__global__ __launch_bounds__(256) void k5b_h2(const float* __restrict__ b2,
                                              float* __restrict__ ws) {
  __shared__ __align__(16) unsigned short vT[128 * 64];   // rows fl (128B), swizzled
  int b = blockIdx.x, o = blockIdx.y, g = blockIdx.z, t = threadIdx.x;
  const unsigned short* vbp = (const unsigned short*)(ws + OFF_A) +
                              (size_t)(b * 32 + o) * 32768;
  const uint4* vb4 = (const uint4*)vbp;
  unsigned char* vTw = (unsigned char*)vT;
  // stage V^T: vT[fl][p] = v[p][g*128+fl]; in-row byte ^= (((fl^(fl>>3))&7)<<4)
  for (int i = t; i < 1024; i += 256) {
    int p = i >> 4, u = i & 15;
    uint4 val = vb4[p * 64 + g * 16 + u];
    const unsigned short* hv = (const unsigned short*)&val;
#pragma unroll
    for (int e = 0; e < 8; ++e) {
      int fl = u * 8 + e;
      int addr = fl * 128 + ((p * 2) ^ ((((fl & 7) ^ (fl >> 3)) & 7) << 4));
      *(unsigned short*)(vTw + addr) = hv[e];
    }
  }
  // A fragments direct from global (L2-hot, shared by all blocks of this g)
  int w = t >> 6, l = t & 63, ll = l & 15, lhi = l >> 4;
  const unsigned short* a2h = (const unsigned short*)(ws + OFF_A2H) + g * 4096;
  const unsigned short* a2l = (const unsigned short*)(ws + OFF_A2L) + g * 4096;
  bf16x8 Ah[4][2], Al[4][2];
#pragma unroll
  for (int Mt = 0; Mt < 4; ++Mt)
#pragma unroll
    for (int ks = 0; ks < 2; ++ks) {
      int idx = (Mt * 16 + ll) * 64 + ks * 32 + lhi * 8;
      Ah[Mt][ks] = *(const bf16x8*)(a2h + idx);
      Al[Mt][ks] = *(const bf16x8*)(a2l + idx);
    }
  float bias = b2[o];
  __syncthreads();
  unsigned short* h2T = (unsigned short*)(ws + OFF_B) + (size_t)(b * 32 + o) * 32768;
  const unsigned char* vTr = (const unsigned char*)vT;
#pragma unroll
  for (int fi = 0; fi < 2; ++fi) {
    int fgl = w * 2 + fi;
    int fl = fgl * 16 + ll;
    int swz = (((fl & 7) ^ (fl >> 3)) & 7) << 4;
    bf16x8 Bf[2];
#pragma unroll
    for (int ks = 0; ks < 2; ++ks)
      Bf[ks] = *(const bf16x8*)(vTr + fl * 128 + ((ks * 64 + lhi * 16) ^ swz));
#pragma unroll
    for (int Mt = 0; Mt < 4; ++Mt) {
      f32x4 acc = {0.f, 0.f, 0.f, 0.f};
      acc = __builtin_amdgcn_mfma_f32_16x16x32_bf16(Ah[Mt][0], Bf[0], acc, 0, 0, 0);
      acc = __builtin_amdgcn_mfma_f32_16x16x32_bf16(Al[Mt][0], Bf[0], acc, 0, 0, 0);
      acc = __builtin_amdgcn_mfma_f32_16x16x32_bf16(Ah[Mt][1], Bf[1], acc, 0, 0, 0);
      acc = __builtin_amdgcn_mfma_f32_16x16x32_bf16(Al[Mt][1], Bf[1], acc, 0, 0, 0);
      int f = g * 128 + fgl * 16 + ll;    // D col = lane&15
      int n0 = Mt * 16 + lhi * 4;         // D row = (lane>>4)*4 + reg
      unsigned short hs[4];
#pragma unroll
      for (int i2 = 0; i2 < 4; ++i2) hs[i2] = f2bf(acc[i2] + bias);
      *(short4v*)(h2T + f * 64 + n0) = *(short4v*)hs;
    }
  }
}

// ------- conv2 via bf16 MFMA implicit GEMM + tb2 + relu + mean partial -------
#define L_TWB 66304    // 32 q * 912B = 29184
#define L_RED 95488    // 8 floats
__global__ __launch_bounds__(512) void k6_conv2(const float* __restrict__ tb2,
                                                float* __restrict__ ws) {
  __shared__ __align__(16) unsigned char sm[95520];
  int b = blockIdx.x, c = blockIdx.y, t = threadIdx.x;
  const uint4* h2T4 = (const uint4*)((const unsigned short*)(ws + OFF_B) +
                                     (size_t)(b * 32 + c) * 32768);
  for (int ci = t; ci < 4144; ci += 512) {
    int r = ci >> 3, slot = ci & 7;
    int f = r - 3;
    uint4 val = make_uint4(0u, 0u, 0u, 0u);
    if (f >= 0 && f < 512) val = h2T4[f * 8 + slot];
    *(uint4*)(sm + r * 128 + ((slot ^ (r & 7)) << 4)) = val;
  }
  const uint4* twg = (const uint4*)(ws + OFF_TWB);
  for (int ci = t; ci < 1792; ci += 512) {
    int q = ci / 56, rem = ci - q * 56;
    *(uint4*)(sm + L_TWB + q * 912 + rem * 16) = twg[ci];
  }
  __syncthreads();
  int w = t >> 6, l = t & 63;
  int ll = l & 15, lhi = l >> 4;
  bf16x8 A[2][14];
#pragma unroll
  for (int Mt = 0; Mt < 2; ++Mt)
#pragma unroll
    for (int ks = 0; ks < 14; ++ks) {
      int q = Mt * 16 + ll;
      A[Mt][ks] = *(const bf16x8*)(sm + L_TWB + q * 912 + (ks >> 1) * 128 +
                                   (ks & 1) * 64 + lhi * 16);
    }
  f32x4 zero = {0.f, 0.f, 0.f, 0.f};
  f32x4 acc[2][4];
#pragma unroll
  for (int Mt = 0; Mt < 2; ++Mt)
#pragma unroll
    for (int Nt = 0; Nt < 4; ++Nt) acc[Mt][Nt] = zero;
  int rbase = w * 64 + ll;
#pragma unroll
  for (int ks = 0; ks < 14; ++ks) {
    int rb = rbase + (ks >> 1);
    int x = (((ks & 1) * 4 + lhi) ^ (rb & 7)) << 4;
#pragma unroll
    for (int Nt = 0; Nt < 4; ++Nt) {
      bf16x8 Bf = *(const bf16x8*)(sm + (rb + Nt * 16) * 128 + x);
      acc[0][Nt] = __builtin_amdgcn_mfma_f32_16x16x32_bf16(A[0][ks], Bf, acc[0][Nt], 0, 0, 0);
      acc[1][Nt] = __builtin_amdgcn_mfma_f32_16x16x32_bf16(A[1][ks], Bf, acc[1][Nt], 0, 0, 0);
    }
  }
  float tbv[8];
#pragma unroll
  for (int Mt = 0; Mt < 2; ++Mt)
#pragma unroll
    for (int i = 0; i < 4; ++i) tbv[Mt * 4 + i] = tb2[Mt * 16 + lhi * 4 + i];
  float s = 0.f;
#pragma unroll
  for (int Mt = 0; Mt < 2; ++Mt)
#pragma unroll
    for (int Nt = 0; Nt < 4; ++Nt)
#pragma unroll
      for (int i = 0; i < 4; ++i)
        s += fmaxf(acc[Mt][Nt][i] + tbv[Mt * 4 + i], 0.0f);
#pragma unroll
  for (int off = 32; off > 0; off >>= 1) s += __shfl_down(s, off, 64);
  float* red = (float*)(sm + L_RED);
  if (l == 0) red[w] = s;
  __syncthreads();
  if (t == 0) {
    float tot = 0.f;
    for (int i = 0; i < 8; ++i) tot += red[i];
    ws[OFF_PART + b * 32 + c] = tot;
  }
}

// ---------------- final: feat mean + linear ----------------
__global__ __launch_bounds__(256) void k7_final(const float* __restrict__ Wout,
    const float* __restrict__ bout, const float* __restrict__ ws, float* __restrict__ out) {
  __shared__ float feat[512];
  int t = threadIdx.x;
  for (int i = t; i < 512; i += 256)
    feat[i] = ws[OFF_PART + i] * (1.0f / 16384.0f);
  __syncthreads();
  if (t < 160) {
    int bb = t / 10, j = t - bb * 10;
    float acc = bout[j];
    for (int c = 0; c < 32; ++c) acc += feat[bb * 32 + c] * Wout[j * 32 + c];
    out[t] = acc;
  }
}

extern "C" void kernel_launch(void* const* d_in, const int* in_sizes, int n_in,
                              void* d_out, int out_size, void* d_ws, size_t ws_size,
                              hipStream_t stream) {
  const float* x    = (const float*)d_in[0];
  const float* adj  = (const float*)d_in[1];
  const float* W1   = (const float*)d_in[2];
  const float* b1   = (const float*)d_in[3];
  const float* tw1  = (const float*)d_in[4];
  const float* tb1  = (const float*)d_in[5];
  const float* rp1  = (const float*)d_in[6];
  const float* W2   = (const float*)d_in[7];
  const float* b2   = (const float*)d_in[8];
  const float* tw2  = (const float*)d_in[9];
  const float* tb2  = (const float*)d_in[10];
  // d_in[11] = rp2 : unused (second pooled adjacency is dead in the reference)
  const float* Wout = (const float*)d_in[12];
  const float* bout = (const float*)d_in[13];
  float* out = (float*)d_out;
  float* ws = (float*)d_ws;

  p1_kernel <<<93, 256, 0, stream>>>(adj, tw1, rp1, tw2, ws);
  p1b_kernel<<<256, 256, 0, stream>>>(adj, ws);
  p2_kernel <<<128, 256, 0, stream>>>(adj, ws);
  p3a_kernel<<<dim3(4, 16), 256, 0, stream>>>(ws);
  p3b_kernel<<<4, 256, 0, stream>>>(ws);
  k1_y      <<<dim3(16, 32, 2), 256, 0, stream>>>(x, ws);
  k2_z      <<<dim3(16, 9, 8), 256, 0, stream>>>(tw1, ws);
  k45_fused <<<dim3(16, 64), 256, 0, stream>>>(W1, b1, tb1, W2, ws);
  k5b_h2    <<<dim3(16, 32, 4), 256, 0, stream>>>(b2, ws);
  k6_conv2  <<<dim3(16, 32), 512, 0, stream>>>(tb2, ws);
  k7_final  <<<1, 256, 0, stream>>>(Wout, bout, ws, out);
}

// Round 7
// 149.147 us; speedup vs baseline: 2.4401x; 1.2075x over previous
//
#include <hip/hip_runtime.h>
#include <math.h>

// Problem sizes: B=16, Cin=1, CH=32, N0=128, F=512, G=4, N1=64, k1=9, N2=32, k2=7, NC=10
// Workspace offsets (float units)
#define OFF_D1   0          // 512
#define OFF_S1   512        // 8192  : s1[p][n]
#define OFF_T1   8704       // 576   : T1[p][k]
#define OFF_TWB  9280       // 7168 slots = 14336 ushort : bf16 tw2 packed [q][k][n]
#define OFF_T    16448      // 32768 : t[g][n][q]
#define OFF_A2   49216      // 16384 : ap[g][p][q] scratch (pre-normalization)
#define OFF_A2H  65600      // 8192 slots : bf16 hi of anorm2 [g][n][m]
#define OFF_A2L  73792      // 8192 slots : bf16 lo residual [g][n][m]
#define OFF_PART 81984      // 512   : partial sums [b][c]
#define OFF_AN1  82496      // 65536 : anorm1[g][n][m]
#define OFF_C1H  148032     // 147456 slots = 294912 ushort : bf16 hi C1[g][r][m]
#define OFF_C1L  295488     // 147456 slots : bf16 lo residual
#define OFF_XTH  442944     // 524288 slots = 1048576 ushort : xT hi [b][g][f][m]
#define OFF_XTL  967232     // 524288 slots : xT lo
#define OFF_A    1491520    // 8388608 slots : v bf16 plain [b,o][p][f]
#define OFF_B    9880128    // 8388608 slots : h2T bf16 [b,o][f][n]
#define OFF_Z    18268736   // 4718592 : z fp32 [b][r=p*9+k][f]

typedef short bf16x8 __attribute__((ext_vector_type(8)));
typedef short short4v __attribute__((ext_vector_type(4)));
typedef float f32x4 __attribute__((ext_vector_type(4)));

static __device__ __forceinline__ unsigned short f2bf(float x) {
  union { float f; unsigned u; } v; v.f = x;
  unsigned r = v.u + 0x7FFF + ((v.u >> 16) & 1);   // RNE
  return (unsigned short)(r >> 16);
}
static __device__ __forceinline__ float bf2f(unsigned short h) {
  union { unsigned u; float f; } v; v.u = ((unsigned)h) << 16;
  return v.f;
}

// ---------------- prep ----------------
__global__ __launch_bounds__(256) void p1_kernel(const float* __restrict__ adj,
    const float* __restrict__ tw1, const float* __restrict__ rp1,
    const float* __restrict__ tw2, float* __restrict__ ws) {
  int idx = blockIdx.x * 256 + threadIdx.x;
  if (idx < 512) {
    int g = idx >> 7, n = idx & 127;
    const float* row = adj + (g * 128 + n) * 128;
    float s = 1.0f;
    for (int m = 0; m < 128; ++m) s += row[m];
    ws[OFF_D1 + idx] = 1.0f / sqrtf(fmaxf(s, 1.0f));
  } else if (idx < 8704) {
    int r = idx - 512; int p = r >> 7, n = r & 127;
    const float* tp = tw1 + (p * 128 + n) * 9;
    float s = 0.f;
#pragma unroll
    for (int k = 0; k < 9; ++k) s += tp[k] * rp1[k];
    ws[OFF_S1 + r] = s;
  } else if (idx < 9280) {
    int r = idx - 8704; int p = r / 9, k = r - p * 9;
    float s = 0.f;
    for (int n = 0; n < 128; ++n) s += tw1[(p * 128 + n) * 9 + k];
    ws[OFF_T1 + r] = s;
  } else if (idx < 23616) {              // twB bf16 [q][k][n]: q*448 + k*64 + n
    int r = idx - 9280;
    int q = r / 448, rem = r - q * 448;
    int k = rem >> 6, n = rem & 63;
    ((unsigned short*)(ws + OFF_TWB))[r] = f2bf(tw2[(q * 64 + n) * 7 + k]);
  }
}

__global__ __launch_bounds__(256) void p1b_kernel(const float* __restrict__ adj,
                                                  float* __restrict__ ws) {
  int idx = blockIdx.x * 256 + threadIdx.x;   // 65536
  int g = idx >> 14, n = (idx >> 7) & 127, m = idx & 127;
  float v = adj[idx] + (n == m ? 1.0f : 0.0f);
  ws[OFF_AN1 + idx] = ws[OFF_D1 + g * 128 + n] * ws[OFF_D1 + g * 128 + m] * v;
}

__global__ __launch_bounds__(256) void p2_kernel(const float* __restrict__ adj,
                                                 float* __restrict__ ws) {
  int idx = blockIdx.x * 256 + threadIdx.x;   // 32768
  int g = idx >> 13, n = (idx >> 6) & 127, q = idx & 63;
  const float* row = adj + (g * 128 + n) * 128;
  const float* s1 = ws + OFF_S1 + q * 128;
  float s = 0.f;
  for (int m = 0; m < 128; ++m) s += row[m] * s1[m];
  ws[OFF_T + idx] = s;
}

// ap[g][p][q] = sum_n s1[p][n] * t[g][n][q]
__global__ __launch_bounds__(256) void p3a_kernel(float* __restrict__ ws) {
  int g = blockIdx.x, pt = blockIdx.y, t = threadIdx.x;
  int pp = t >> 6, q = t & 63;
  int p = pt * 4 + pp;
  const float* s1 = ws + OFF_S1 + p * 128;
  const float* tg = ws + OFF_T + g * 8192;
  float s = 0.f;
#pragma unroll 4
  for (int n = 0; n < 128; ++n) s += s1[n] * tg[n * 64 + q];
  ws[OFF_A2 + g * 4096 + p * 64 + q] = s;
}

// normalize pooled adjacency, emit split-bf16 (hi + lo residual)
__global__ __launch_bounds__(256) void p3b_kernel(float* __restrict__ ws) {
  __shared__ float ap[4096];
  __shared__ float d2[64];
  int g = blockIdx.x, t = threadIdx.x;
  for (int i = t; i < 4096; i += 256) ap[i] = ws[OFF_A2 + g * 4096 + i];
  __syncthreads();
  if (t < 64) {
    float s = 1.0f;
    for (int q = 0; q < 64; ++q) s += ap[t * 64 + q];
    d2[t] = 1.0f / sqrtf(fmaxf(s, 1.0f));
  }
  __syncthreads();
  for (int i = t; i < 4096; i += 256) {
    int p = i >> 6, q = i & 63;
    float fullv = d2[p] * d2[q] * (ap[i] + (p == q ? 1.0f : 0.0f));
    unsigned short hi = f2bf(fullv);
    float lo = fullv - bf2f(hi);
    ((unsigned short*)(ws + OFF_A2H))[g * 4096 + i] = hi;
    ((unsigned short*)(ws + OFF_A2L))[g * 4096 + i] = f2bf(lo);
  }
}

// C1[g][r][m] = sum_n tw1[p,n,k] * anorm1[g,n,m]  (r = p*9+k), split-bf16 out
__global__ __launch_bounds__(256) void pC1_kernel(const float* __restrict__ tw1,
                                                  float* __restrict__ ws) {
  int g = blockIdx.x, rb = blockIdx.y, t = threadIdx.x;
  int r = rb * 2 + (t >> 7), m = t & 127;
  int p = r / 9, k = r - p * 9;
  const float* an = ws + OFF_AN1 + g * 16384;
  float s = 0.f;
#pragma unroll 4
  for (int n = 0; n < 128; ++n)
    s += tw1[(p * 128 + n) * 9 + k] * an[n * 128 + m];
  unsigned short hi = f2bf(s);
  float lo = s - bf2f(hi);
  ((unsigned short*)(ws + OFF_C1H))[((size_t)g * 576 + r) * 128 + m] = hi;
  ((unsigned short*)(ws + OFF_C1L))[((size_t)g * 576 + r) * 128 + m] = f2bf(lo);
}

// xT[b][g][f][m] split-bf16: transpose x via padded LDS
__global__ __launch_bounds__(256) void pxt_kernel(const float* __restrict__ x,
                                                  float* __restrict__ ws) {
  __shared__ float XP[128 * 129];
  int b = blockIdx.x, g = blockIdx.y, t = threadIdx.x;
#pragma unroll
  for (int i = 0; i < 16; ++i) {
    int e = i * 256 + t;                 // 4096 float4s: f4 = e&31, m = e>>5
    int f4 = e & 31, m = e >> 5;
    float4 v = *(const float4*)&x[(size_t)(b * 128 + m) * 512 + g * 128 + f4 * 4];
    XP[m * 129 + f4 * 4 + 0] = v.x;
    XP[m * 129 + f4 * 4 + 1] = v.y;
    XP[m * 129 + f4 * 4 + 2] = v.z;
    XP[m * 129 + f4 * 4 + 3] = v.w;
  }
  __syncthreads();
  unsigned short* XH = (unsigned short*)(ws + OFF_XTH) + (size_t)(b * 4 + g) * 16384;
  unsigned short* XL = (unsigned short*)(ws + OFF_XTL) + (size_t)(b * 4 + g) * 16384;
#pragma unroll
  for (int i = 0; i < 8; ++i) {
    int e = i * 256 + t;                 // 2048 uint4 outs: f = e>>4, m8 = e&15
    int f = e >> 4, m8 = e & 15;
    unsigned short hs[8], ls[8];
#pragma unroll
    for (int j = 0; j < 8; ++j) {
      float v = XP[(m8 * 8 + j) * 129 + f];
      unsigned short h = f2bf(v);
      hs[j] = h;
      ls[j] = f2bf(v - bf2f(h));
    }
    *(uint4*)&XH[f * 128 + m8 * 8] = *(uint4*)hs;
    *(uint4*)&XL[f * 128 + m8 * 8] = *(uint4*)ls;
  }
}

// ---- z[b][r][f] = sum_m C1[g(f)][r][m] * x[b][m][f] via 3-term split MFMA ----
__global__ __launch_bounds__(512) void kz_mfma(float* __restrict__ ws) {
  __shared__ __align__(16) unsigned char smH[32768];   // XT tile rows f, 256B, swizzled
  __shared__ __align__(16) unsigned char smL[32768];
  int b = blockIdx.x, rt = blockIdx.y, g = blockIdx.z, t = threadIdx.x;
  const uint4* XH = (const uint4*)((const unsigned short*)(ws + OFF_XTH) +
                                   (size_t)(b * 4 + g) * 16384);
  const uint4* XL = (const uint4*)((const unsigned short*)(ws + OFF_XTL) +
                                   (size_t)(b * 4 + g) * 16384);
#pragma unroll
  for (int i = 0; i < 4; ++i) {
    int e = i * 512 + t;                 // 2048: f = e>>4, s = e&15
    int f = e >> 4, s = e & 15;
    int slot = s ^ (f & 7);
    *(uint4*)(smH + f * 256 + slot * 16) = XH[e];
    *(uint4*)(smL + f * 256 + slot * 16) = XL[e];
  }
  int w = t >> 6, l = t & 63, ll = l & 15, lhi = l >> 4;
  int wm = w & 3, wn = w >> 2;
  const unsigned short* c1h = (const unsigned short*)(ws + OFF_C1H) +
                              ((size_t)g * 576 + rt * 64 + wm * 16 + ll) * 128;
  const unsigned short* c1l = (const unsigned short*)(ws + OFF_C1L) +
                              ((size_t)g * 576 + rt * 64 + wm * 16 + ll) * 128;
  bf16x8 Ah[4], Al[4];
#pragma unroll
  for (int ks = 0; ks < 4; ++ks) {
    Ah[ks] = *(const bf16x8*)(c1h + ks * 32 + lhi * 8);
    Al[ks] = *(const bf16x8*)(c1l + ks * 32 + lhi * 8);
  }
  __syncthreads();
  float* zb = ws + OFF_Z + ((size_t)b * 576 + rt * 64 + wm * 16) * 512 + g * 128 + wn * 64;
#pragma unroll
  for (int Nt = 0; Nt < 4; ++Nt) {
    int f = wn * 64 + Nt * 16 + ll;
    bf16x8 Bh[4], Bl[4];
#pragma unroll
    for (int ks = 0; ks < 4; ++ks) {
      int slot = (ks * 4 + lhi) ^ (f & 7);
      Bh[ks] = *(const bf16x8*)(smH + f * 256 + slot * 16);
      Bl[ks] = *(const bf16x8*)(smL + f * 256 + slot * 16);
    }
    f32x4 acc = {0.f, 0.f, 0.f, 0.f};
#pragma unroll
    for (int ks = 0; ks < 4; ++ks) {
      acc = __builtin_amdgcn_mfma_f32_16x16x32_bf16(Ah[ks], Bh[ks], acc, 0, 0, 0);
      acc = __builtin_amdgcn_mfma_f32_16x16x32_bf16(Ah[ks], Bl[ks], acc, 0, 0, 0);
      acc = __builtin_amdgcn_mfma_f32_16x16x32_bf16(Al[ks], Bh[ks], acc, 0, 0, 0);
    }
#pragma unroll
    for (int i = 0; i < 4; ++i)
      zb[(lhi * 4 + i) * 512 + Nt * 16 + ll] = acc[i];
  }
}

// -------- fused: x2[c,f] = relu(sum_k W1*z + b1*Tsum + tb1) ; v[o,f] = sum_c W2*x2
__global__ __launch_bounds__(256) void k45_fused(const float* __restrict__ W1,
    const float* __restrict__ b1, const float* __restrict__ tb1,
    const float* __restrict__ W2, float* __restrict__ ws) {
  __shared__ float W1s[128];
  __shared__ float b1s[32];
  __shared__ float T1s[9];
  __shared__ __align__(16) float W2s[4096];
  int b = blockIdx.x, p = blockIdx.y, t = threadIdx.x;
  for (int i = t; i < 4096; i += 256) W2s[i] = W2[i];
  if (t < 128) W1s[t] = W1[t];
  else if (t < 160) b1s[t - 128] = b1[t - 128];
  else if (t < 169) T1s[t - 160] = ws[OFF_T1 + p * 9 + (t - 160)];
  float tb = tb1[p];
  __syncthreads();
  const float* z = ws + OFF_Z + (size_t)b * 294912 + (size_t)p * 4608;
  unsigned short* vb = (unsigned short*)(ws + OFF_A);
  for (int pass = 0; pass < 2; ++pass) {
    int f = pass * 256 + t;
    float zv[9]; int gk[9];
    float tsum = 0.f;
#pragma unroll
    for (int k = 0; k < 9; ++k) {
      int fp = f + k - 4;
      bool val = (fp >= 0 && fp < 512);
      zv[k] = val ? z[k * 512 + fp] : 0.0f;
      gk[k] = val ? (fp >> 7) : 0;
      tsum += val ? T1s[k] : 0.0f;
    }
    float acc[32];
#pragma unroll
    for (int c = 0; c < 32; ++c) acc[c] = b1s[c] * tsum + tb;
#pragma unroll
    for (int k = 0; k < 9; ++k) {
      const float4* Wc = (const float4*)&W1s[gk[k] * 32];
      float zk = zv[k];
#pragma unroll
      for (int c4 = 0; c4 < 8; ++c4) {
        float4 wv = Wc[c4];
        acc[c4 * 4 + 0] += wv.x * zk;
        acc[c4 * 4 + 1] += wv.y * zk;
        acc[c4 * 4 + 2] += wv.z * zk;
        acc[c4 * 4 + 3] += wv.w * zk;
      }
    }
#pragma unroll
    for (int c = 0; c < 32; ++c) acc[c] = fmaxf(acc[c], 0.0f);   // x2 in regs
    int g = f >> 7;
    const float4* Wg4 = (const float4*)(W2s + g * 1024);
#pragma unroll 2
    for (int o = 0; o < 32; ++o) {
      float s = 0.f;
#pragma unroll
      for (int c4 = 0; c4 < 8; ++c4) {
        float4 wv = Wg4[o * 8 + c4];
        s += wv.x * acc[c4 * 4] + wv.y * acc[c4 * 4 + 1] + wv.z * acc[c4 * 4 + 2] + wv.w * acc[c4 * 4 + 3];
      }
      vb[((b * 32 + o) * 64 + p) * 512 + f] = f2bf(s);
    }
  }
}

// ---- h2T[b,o,f,n] (bf16) = sum_m anorm2[g(f),n,m]*v[b,o,m,f] + b2[o] via MFMA ----
__global__ __launch_bounds__(256) void k5b_h2(const float* __restrict__ b2,
                                              float* __restrict__ ws) {
  __shared__ __align__(16) unsigned short vT[128 * 64];   // rows fl (128B), swizzled
  int b = blockIdx.x, o = blockIdx.y, g = blockIdx.z, t = threadIdx.x;
  const unsigned short* vbp = (const unsigned short*)(ws + OFF_A) +
                              (size_t)(b * 32 + o) * 32768;
  const uint4* vb4 = (const uint4*)vbp;
  unsigned char* vTw = (unsigned char*)vT;
  for (int i = t; i < 1024; i += 256) {
    int p = i >> 4, u = i & 15;
    uint4 val = vb4[p * 64 + g * 16 + u];
    const unsigned short* hv = (const unsigned short*)&val;
#pragma unroll
    for (int e = 0; e < 8; ++e) {
      int fl = u * 8 + e;
      int addr = fl * 128 + ((p * 2) ^ ((((fl & 7) ^ (fl >> 3)) & 7) << 4));
      *(unsigned short*)(vTw + addr) = hv[e];
    }
  }
  int w = t >> 6, l = t & 63, ll = l & 15, lhi = l >> 4;
  const unsigned short* a2h = (const unsigned short*)(ws + OFF_A2H) + g * 4096;
  const unsigned short* a2l = (const unsigned short*)(ws + OFF_A2L) + g * 4096;
  bf16x8 Ah[4][2], Al[4][2];
#pragma unroll
  for (int Mt = 0; Mt < 4; ++Mt)
#pragma unroll
    for (int ks = 0; ks < 2; ++ks) {
      int idx = (Mt * 16 + ll) * 64 + ks * 32 + lhi * 8;
      Ah[Mt][ks] = *(const bf16x8*)(a2h + idx);
      Al[Mt][ks] = *(const bf16x8*)(a2l + idx);
    }
  float bias = b2[o];
  __syncthreads();
  unsigned short* h2T = (unsigned short*)(ws + OFF_B) + (size_t)(b * 32 + o) * 32768;
  const unsigned char* vTr = (const unsigned char*)vT;
#pragma unroll
  for (int fi = 0; fi < 2; ++fi) {
    int fgl = w * 2 + fi;
    int fl = fgl * 16 + ll;
    int swz = (((fl & 7) ^ (fl >> 3)) & 7) << 4;
    bf16x8 Bf[2];
#pragma unroll
    for (int ks = 0; ks < 2; ++ks)
      Bf[ks] = *(const bf16x8*)(vTr + fl * 128 + ((ks * 64 + lhi * 16) ^ swz));
#pragma unroll
    for (int Mt = 0; Mt < 4; ++Mt) {
      f32x4 acc = {0.f, 0.f, 0.f, 0.f};
      acc = __builtin_amdgcn_mfma_f32_16x16x32_bf16(Ah[Mt][0], Bf[0], acc, 0, 0, 0);
      acc = __builtin_amdgcn_mfma_f32_16x16x32_bf16(Al[Mt][0], Bf[0], acc, 0, 0, 0);
      acc = __builtin_amdgcn_mfma_f32_16x16x32_bf16(Ah[Mt][1], Bf[1], acc, 0, 0, 0);
      acc = __builtin_amdgcn_mfma_f32_16x16x32_bf16(Al[Mt][1], Bf[1], acc, 0, 0, 0);
      int f = g * 128 + fgl * 16 + ll;
      int n0 = Mt * 16 + lhi * 4;
      unsigned short hs[4];
#pragma unroll
      for (int i2 = 0; i2 < 4; ++i2) hs[i2] = f2bf(acc[i2] + bias);
      *(short4v*)(h2T + f * 64 + n0) = *(short4v*)hs;
    }
  }
}

// ------- conv2 via bf16 MFMA implicit GEMM + tb2 + relu + mean partial -------
#define L_TWB 66304    // 32 q * 912B = 29184
#define L_RED 95488    // 8 floats
__global__ __launch_bounds__(512) void k6_conv2(const float* __restrict__ tb2,
                                                float* __restrict__ ws) {
  __shared__ __align__(16) unsigned char sm[95520];
  int b = blockIdx.x, c = blockIdx.y, t = threadIdx.x;
  const uint4* h2T4 = (const uint4*)((const unsigned short*)(ws + OFF_B) +
                                     (size_t)(b * 32 + c) * 32768);
  for (int ci = t; ci < 4144; ci += 512) {
    int r = ci >> 3, slot = ci & 7;
    int f = r - 3;
    uint4 val = make_uint4(0u, 0u, 0u, 0u);
    if (f >= 0 && f < 512) val = h2T4[f * 8 + slot];
    *(uint4*)(sm + r * 128 + ((slot ^ (r & 7)) << 4)) = val;
  }
  const uint4* twg = (const uint4*)(ws + OFF_TWB);
  for (int ci = t; ci < 1792; ci += 512) {
    int q = ci / 56, rem = ci - q * 56;
    *(uint4*)(sm + L_TWB + q * 912 + rem * 16) = twg[ci];
  }
  __syncthreads();
  int w = t >> 6, l = t & 63;
  int ll = l & 15, lhi = l >> 4;
  bf16x8 A[2][14];
#pragma unroll
  for (int Mt = 0; Mt < 2; ++Mt)
#pragma unroll
    for (int ks = 0; ks < 14; ++ks) {
      int q = Mt * 16 + ll;
      A[Mt][ks] = *(const bf16x8*)(sm + L_TWB + q * 912 + (ks >> 1) * 128 +
                                   (ks & 1) * 64 + lhi * 16);
    }
  f32x4 zero = {0.f, 0.f, 0.f, 0.f};
  f32x4 acc[2][4];
#pragma unroll
  for (int Mt = 0; Mt < 2; ++Mt)
#pragma unroll
    for (int Nt = 0; Nt < 4; ++Nt) acc[Mt][Nt] = zero;
  int rbase = w * 64 + ll;
#pragma unroll
  for (int ks = 0; ks < 14; ++ks) {
    int rb = rbase + (ks >> 1);
    int x = (((ks & 1) * 4 + lhi) ^ (rb & 7)) << 4;
#pragma unroll
    for (int Nt = 0; Nt < 4; ++Nt) {
      bf16x8 Bf = *(const bf16x8*)(sm + (rb + Nt * 16) * 128 + x);
      acc[0][Nt] = __builtin_amdgcn_mfma_f32_16x16x32_bf16(A[0][ks], Bf, acc[0][Nt], 0, 0, 0);
      acc[1][Nt] = __builtin_amdgcn_mfma_f32_16x16x32_bf16(A[1][ks], Bf, acc[1][Nt], 0, 0, 0);
    }
  }
  float tbv[8];
#pragma unroll
  for (int Mt = 0; Mt < 2; ++Mt)
#pragma unroll
    for (int i = 0; i < 4; ++i) tbv[Mt * 4 + i] = tb2[Mt * 16 + lhi * 4 + i];
  float s = 0.f;
#pragma unroll
  for (int Mt = 0; Mt < 2; ++Mt)
#pragma unroll
    for (int Nt = 0; Nt < 4; ++Nt)
#pragma unroll
      for (int i = 0; i < 4; ++i)
        s += fmaxf(acc[Mt][Nt][i] + tbv[Mt * 4 + i], 0.0f);
#pragma unroll
  for (int off = 32; off > 0; off >>= 1) s += __shfl_down(s, off, 64);
  float* red = (float*)(sm + L_RED);
  if (l == 0) red[w] = s;
  __syncthreads();
  if (t == 0) {
    float tot = 0.f;
    for (int i = 0; i < 8; ++i) tot += red[i];
    ws[OFF_PART + b * 32 + c] = tot;
  }
}

// ---------------- final: feat mean + linear ----------------
__global__ __launch_bounds__(256) void k7_final(const float* __restrict__ Wout,
    const float* __restrict__ bout, const float* __restrict__ ws, float* __restrict__ out) {
  __shared__ float feat[512];
  int t = threadIdx.x;
  for (int i = t; i < 512; i += 256)
    feat[i] = ws[OFF_PART + i] * (1.0f / 16384.0f);
  __syncthreads();
  if (t < 160) {
    int bb = t / 10, j = t - bb * 10;
    float acc = bout[j];
    for (int c = 0; c < 32; ++c) acc += feat[bb * 32 + c] * Wout[j * 32 + c];
    out[t] = acc;
  }
}

extern "C" void kernel_launch(void* const* d_in, const int* in_sizes, int n_in,
                              void* d_out, int out_size, void* d_ws, size_t ws_size,
                              hipStream_t stream) {
  const float* x    = (const float*)d_in[0];
  const float* adj  = (const float*)d_in[1];
  const float* W1   = (const float*)d_in[2];
  const float* b1   = (const float*)d_in[3];
  const float* tw1  = (const float*)d_in[4];
  const float* tb1  = (const float*)d_in[5];
  const float* rp1  = (const float*)d_in[6];
  const float* W2   = (const float*)d_in[7];
  const float* b2   = (const float*)d_in[8];
  const float* tw2  = (const float*)d_in[9];
  const float* tb2  = (const float*)d_in[10];
  // d_in[11] = rp2 : unused (second pooled adjacency is dead in the reference)
  const float* Wout = (const float*)d_in[12];
  const float* bout = (const float*)d_in[13];
  float* out = (float*)d_out;
  float* ws = (float*)d_ws;

  p1_kernel <<<93, 256, 0, stream>>>(adj, tw1, rp1, tw2, ws);
  p1b_kernel<<<256, 256, 0, stream>>>(adj, ws);
  pxt_kernel<<<dim3(16, 4), 256, 0, stream>>>(x, ws);
  p2_kernel <<<128, 256, 0, stream>>>(adj, ws);
  p3a_kernel<<<dim3(4, 16), 256, 0, stream>>>(ws);
  p3b_kernel<<<4, 256, 0, stream>>>(ws);
  pC1_kernel<<<dim3(4, 288), 256, 0, stream>>>(tw1, ws);
  kz_mfma   <<<dim3(16, 9, 4), 512, 0, stream>>>(ws);
  k45_fused <<<dim3(16, 64), 256, 0, stream>>>(W1, b1, tb1, W2, ws);
  k5b_h2    <<<dim3(16, 32, 4), 256, 0, stream>>>(b2, ws);
  k6_conv2  <<<dim3(16, 32), 512, 0, stream>>>(tb2, ws);
  k7_final  <<<1, 256, 0, stream>>>(Wout, bout, ws, out);
}

// Round 8
// 116.118 us; speedup vs baseline: 3.1342x; 1.2844x over previous
//
#include <hip/hip_runtime.h>
#include <math.h>

// Problem sizes: B=16, Cin=1, CH=32, N0=128, F=512, G=4, N1=64, k1=9, N2=32, k2=7, NC=10
// Workspace offsets (float units)
#define OFF_D1   0          // 512
#define OFF_S1   512        // 8192  : s1[p][n]
#define OFF_T1   8704       // 576   : T1[p][k]
#define OFF_TWB  9280       // 7168 slots = 14336 ushort : bf16 tw2 packed [q][k][n]
#define OFF_T    16448      // 32768 : t[g][n][q]
#define OFF_A2   49216      // 16384 : ap[g][p][q] scratch (pre-normalization)
#define OFF_A2H  65600      // 8192 slots : bf16 hi of anorm2 [g][n][m]
#define OFF_A2L  73792      // 8192 slots : bf16 lo residual [g][n][m]
#define OFF_PART 81984      // 512   : partial sums [b][c]
#define OFF_AN1  82496      // 65536 : anorm1[g][n][m]
#define OFF_C1H  148032     // 147456 slots : bf16 hi C1[g][r][m]
#define OFF_C1L  295488     // 147456 slots : bf16 lo residual
#define OFF_XTH  442944     // 524288 slots : xT hi [b][g][f][m]
#define OFF_XTL  967232     // 524288 slots : xT lo
#define OFF_A    1491520    // 8388608 slots : v bf16 plain [b,o][p][f]
#define OFF_B    9880128    // 8388608 slots : h2T bf16 [b,o][f][n]
#define OFF_Z    18268736   // 4718592 : z fp32 [b][r=p*9+k][f]

typedef short bf16x8 __attribute__((ext_vector_type(8)));
typedef short short4v __attribute__((ext_vector_type(4)));
typedef float f32x4 __attribute__((ext_vector_type(4)));

static __device__ __forceinline__ unsigned short f2bf(float x) {
  union { float f; unsigned u; } v; v.f = x;
  unsigned r = v.u + 0x7FFF + ((v.u >> 16) & 1);   // RNE
  return (unsigned short)(r >> 16);
}
static __device__ __forceinline__ float bf2f(unsigned short h) {
  union { unsigned u; float f; } v; v.u = ((unsigned)h) << 16;
  return v.f;
}

// ---------------- PREP1 = p1 (d1,s1,T1,twB) + pxt (x transpose/split) ----------------
__global__ __launch_bounds__(256) void prep1_kernel(const float* __restrict__ adj,
    const float* __restrict__ tw1, const float* __restrict__ rp1,
    const float* __restrict__ tw2, const float* __restrict__ x,
    float* __restrict__ ws) {
  int t = threadIdx.x;
  if (blockIdx.x < 93) {
    int idx = blockIdx.x * 256 + t;
    if (idx < 512) {
      int g = idx >> 7, n = idx & 127;
      const float* row = adj + (g * 128 + n) * 128;
      float s = 1.0f;
      for (int m = 0; m < 128; ++m) s += row[m];
      ws[OFF_D1 + idx] = 1.0f / sqrtf(fmaxf(s, 1.0f));
    } else if (idx < 8704) {
      int r = idx - 512; int p = r >> 7, n = r & 127;
      const float* tp = tw1 + (p * 128 + n) * 9;
      float s = 0.f;
#pragma unroll
      for (int k = 0; k < 9; ++k) s += tp[k] * rp1[k];
      ws[OFF_S1 + r] = s;
    } else if (idx < 9280) {
      int r = idx - 8704; int p = r / 9, k = r - p * 9;
      float s = 0.f;
      for (int n = 0; n < 128; ++n) s += tw1[(p * 128 + n) * 9 + k];
      ws[OFF_T1 + r] = s;
    } else if (idx < 23616) {            // twB bf16 [q][k][n]
      int r = idx - 9280;
      int q = r / 448, rem = r - q * 448;
      int k = rem >> 6, n = rem & 63;
      ((unsigned short*)(ws + OFF_TWB))[r] = f2bf(tw2[(q * 64 + n) * 7 + k]);
    }
  } else {                               // pxt: transpose x via padded LDS
    __shared__ float XP[128 * 129];
    int i = blockIdx.x - 93;
    int b = i >> 2, g = i & 3;
#pragma unroll
    for (int ii = 0; ii < 16; ++ii) {
      int e = ii * 256 + t;
      int f4 = e & 31, m = e >> 5;
      float4 v = *(const float4*)&x[(size_t)(b * 128 + m) * 512 + g * 128 + f4 * 4];
      XP[m * 129 + f4 * 4 + 0] = v.x;
      XP[m * 129 + f4 * 4 + 1] = v.y;
      XP[m * 129 + f4 * 4 + 2] = v.z;
      XP[m * 129 + f4 * 4 + 3] = v.w;
    }
    __syncthreads();
    unsigned short* XH = (unsigned short*)(ws + OFF_XTH) + (size_t)(b * 4 + g) * 16384;
    unsigned short* XL = (unsigned short*)(ws + OFF_XTL) + (size_t)(b * 4 + g) * 16384;
#pragma unroll
    for (int ii = 0; ii < 8; ++ii) {
      int e = ii * 256 + t;
      int f = e >> 4, m8 = e & 15;
      unsigned short hs[8], ls[8];
#pragma unroll
      for (int j = 0; j < 8; ++j) {
        float v = XP[(m8 * 8 + j) * 129 + f];
        unsigned short h = f2bf(v);
        hs[j] = h;
        ls[j] = f2bf(v - bf2f(h));
      }
      *(uint4*)&XH[f * 128 + m8 * 8] = *(uint4*)hs;
      *(uint4*)&XL[f * 128 + m8 * 8] = *(uint4*)ls;
    }
  }
}

// ---------------- PREP2 = p1b (anorm1) + p2 (t) ----------------
__global__ __launch_bounds__(256) void prep2_kernel(const float* __restrict__ adj,
                                                    float* __restrict__ ws) {
  int t = threadIdx.x;
  if (blockIdx.x < 256) {
    int idx = blockIdx.x * 256 + t;      // 65536
    int g = idx >> 14, n = (idx >> 7) & 127, m = idx & 127;
    float v = adj[idx] + (n == m ? 1.0f : 0.0f);
    ws[OFF_AN1 + idx] = ws[OFF_D1 + g * 128 + n] * ws[OFF_D1 + g * 128 + m] * v;
  } else {
    int idx = (blockIdx.x - 256) * 256 + t;   // 32768
    int g = idx >> 13, n = (idx >> 6) & 127, q = idx & 63;
    const float* row = adj + (g * 128 + n) * 128;
    const float* s1 = ws + OFF_S1 + q * 128;
    float s = 0.f;
    for (int m = 0; m < 128; ++m) s += row[m] * s1[m];
    ws[OFF_T + idx] = s;
  }
}

// ---------------- PREP3 = p3a (ap) + pC1 (C1 split-bf16) ----------------
__global__ __launch_bounds__(256) void prep3_kernel(const float* __restrict__ tw1,
                                                    float* __restrict__ ws) {
  int t = threadIdx.x;
  if (blockIdx.x < 64) {                 // p3a
    int g = blockIdx.x & 3, pt = blockIdx.x >> 2;
    int pp = t >> 6, q = t & 63;
    int p = pt * 4 + pp;
    const float* s1 = ws + OFF_S1 + p * 128;
    const float* tg = ws + OFF_T + g * 8192;
    float s = 0.f;
#pragma unroll 4
    for (int n = 0; n < 128; ++n) s += s1[n] * tg[n * 64 + q];
    ws[OFF_A2 + g * 4096 + p * 64 + q] = s;
  } else {                               // pC1
    int i = blockIdx.x - 64;
    int g = i / 288, rb = i - g * 288;
    int r = rb * 2 + (t >> 7), m = t & 127;
    int p = r / 9, k = r - p * 9;
    const float* an = ws + OFF_AN1 + g * 16384;
    float s = 0.f;
#pragma unroll 4
    for (int n = 0; n < 128; ++n)
      s += tw1[(p * 128 + n) * 9 + k] * an[n * 128 + m];
    unsigned short hi = f2bf(s);
    float lo = s - bf2f(hi);
    ((unsigned short*)(ws + OFF_C1H))[((size_t)g * 576 + r) * 128 + m] = hi;
    ((unsigned short*)(ws + OFF_C1L))[((size_t)g * 576 + r) * 128 + m] = f2bf(lo);
  }
}

// ---------------- PREP4 = p3b: normalize pooled adj, split-bf16 ----------------
__global__ __launch_bounds__(256) void prep4_kernel(float* __restrict__ ws) {
  __shared__ float ap[4096];
  __shared__ float d2[64];
  int g = blockIdx.x, t = threadIdx.x;
  for (int i = t; i < 4096; i += 256) ap[i] = ws[OFF_A2 + g * 4096 + i];
  __syncthreads();
  if (t < 64) {
    float s = 1.0f;
    for (int q = 0; q < 64; ++q) s += ap[t * 64 + q];
    d2[t] = 1.0f / sqrtf(fmaxf(s, 1.0f));
  }
  __syncthreads();
  for (int i = t; i < 4096; i += 256) {
    int p = i >> 6, q = i & 63;
    float fullv = d2[p] * d2[q] * (ap[i] + (p == q ? 1.0f : 0.0f));
    unsigned short hi = f2bf(fullv);
    float lo = fullv - bf2f(hi);
    ((unsigned short*)(ws + OFF_A2H))[g * 4096 + i] = hi;
    ((unsigned short*)(ws + OFF_A2L))[g * 4096 + i] = f2bf(lo);
  }
}

// ---- z[b][r][f] = sum_m C1[g(f)][r][m] * x[b][m][f] via 3-term split MFMA ----
__global__ __launch_bounds__(512) void kz_mfma(float* __restrict__ ws) {
  __shared__ __align__(16) unsigned char smH[32768];
  __shared__ __align__(16) unsigned char smL[32768];
  int b = blockIdx.x, rt = blockIdx.y, g = blockIdx.z, t = threadIdx.x;
  const uint4* XH = (const uint4*)((const unsigned short*)(ws + OFF_XTH) +
                                   (size_t)(b * 4 + g) * 16384);
  const uint4* XL = (const uint4*)((const unsigned short*)(ws + OFF_XTL) +
                                   (size_t)(b * 4 + g) * 16384);
#pragma unroll
  for (int i = 0; i < 4; ++i) {
    int e = i * 512 + t;
    int f = e >> 4, s = e & 15;
    int slot = s ^ (f & 7);
    *(uint4*)(smH + f * 256 + slot * 16) = XH[e];
    *(uint4*)(smL + f * 256 + slot * 16) = XL[e];
  }
  int w = t >> 6, l = t & 63, ll = l & 15, lhi = l >> 4;
  int wm = w & 3, wn = w >> 2;
  const unsigned short* c1h = (const unsigned short*)(ws + OFF_C1H) +
                              ((size_t)g * 576 + rt * 64 + wm * 16 + ll) * 128;
  const unsigned short* c1l = (const unsigned short*)(ws + OFF_C1L) +
                              ((size_t)g * 576 + rt * 64 + wm * 16 + ll) * 128;
  bf16x8 Ah[4], Al[4];
#pragma unroll
  for (int ks = 0; ks < 4; ++ks) {
    Ah[ks] = *(const bf16x8*)(c1h + ks * 32 + lhi * 8);
    Al[ks] = *(const bf16x8*)(c1l + ks * 32 + lhi * 8);
  }
  __syncthreads();
  float* zb = ws + OFF_Z + ((size_t)b * 576 + rt * 64 + wm * 16) * 512 + g * 128 + wn * 64;
#pragma unroll
  for (int Nt = 0; Nt < 4; ++Nt) {
    int f = wn * 64 + Nt * 16 + ll;
    bf16x8 Bh[4], Bl[4];
#pragma unroll
    for (int ks = 0; ks < 4; ++ks) {
      int slot = (ks * 4 + lhi) ^ (f & 7);
      Bh[ks] = *(const bf16x8*)(smH + f * 256 + slot * 16);
      Bl[ks] = *(const bf16x8*)(smL + f * 256 + slot * 16);
    }
    f32x4 acc = {0.f, 0.f, 0.f, 0.f};
#pragma unroll
    for (int ks = 0; ks < 4; ++ks) {
      acc = __builtin_amdgcn_mfma_f32_16x16x32_bf16(Ah[ks], Bh[ks], acc, 0, 0, 0);
      acc = __builtin_amdgcn_mfma_f32_16x16x32_bf16(Ah[ks], Bl[ks], acc, 0, 0, 0);
      acc = __builtin_amdgcn_mfma_f32_16x16x32_bf16(Al[ks], Bh[ks], acc, 0, 0, 0);
    }
#pragma unroll
    for (int i = 0; i < 4; ++i)
      zb[(lhi * 4 + i) * 512 + Nt * 16 + ll] = acc[i];
  }
}

// -------- fused: x2[c,f] = relu(sum_k W1*z + b1*Tsum + tb1) ; v = W2*x2 via MFMA
// Each wave owns one g per pass; x2 staged bf16 in LDS [f][c] pitch 40 ushort.
__global__ __launch_bounds__(256) void k45m(const float* __restrict__ W1,
    const float* __restrict__ b1, const float* __restrict__ tb1,
    const float* __restrict__ W2, float* __restrict__ ws) {
  __shared__ float W1s[128];
  __shared__ float b1s[32];
  __shared__ float T1s[9];
  __shared__ __align__(16) unsigned short X2s[256 * 40];
  int b = blockIdx.x, p = blockIdx.y, t = threadIdx.x;
  if (t < 128) W1s[t] = W1[t];
  else if (t < 160) b1s[t - 128] = b1[t - 128];
  else if (t < 169) T1s[t - 160] = ws[OFF_T1 + p * 9 + (t - 160)];
  float tb = tb1[p];
  __syncthreads();
  const float* z = ws + OFF_Z + (size_t)b * 294912 + (size_t)p * 4608;
  unsigned short* vb = (unsigned short*)(ws + OFF_A);
  int w = t >> 6, l = t & 63, ll = l & 15, lhi = l >> 4;
  for (int pass = 0; pass < 2; ++pass) {
    int f = pass * 256 + t;
    float zv[9]; int gk[9];
    float tsum = 0.f;
#pragma unroll
    for (int k = 0; k < 9; ++k) {
      int fp = f + k - 4;
      bool val = (fp >= 0 && fp < 512);
      zv[k] = val ? z[k * 512 + fp] : 0.0f;
      gk[k] = val ? (fp >> 7) : 0;
      tsum += val ? T1s[k] : 0.0f;
    }
    float acc[32];
#pragma unroll
    for (int c = 0; c < 32; ++c) acc[c] = b1s[c] * tsum + tb;
#pragma unroll
    for (int k = 0; k < 9; ++k) {
      const float4* Wc = (const float4*)&W1s[gk[k] * 32];
      float zk = zv[k];
#pragma unroll
      for (int c4 = 0; c4 < 8; ++c4) {
        float4 wv = Wc[c4];
        acc[c4 * 4 + 0] += wv.x * zk;
        acc[c4 * 4 + 1] += wv.y * zk;
        acc[c4 * 4 + 2] += wv.z * zk;
        acc[c4 * 4 + 3] += wv.w * zk;
      }
    }
    __syncthreads();                     // protect X2s from previous pass readers
#pragma unroll
    for (int grp = 0; grp < 4; ++grp) {
      unsigned short hs[8];
#pragma unroll
      for (int j = 0; j < 8; ++j) hs[j] = f2bf(fmaxf(acc[grp * 8 + j], 0.0f));
      *(uint4*)&X2s[t * 40 + grp * 8] = *(uint4*)hs;
    }
    __syncthreads();
    // MFMA phase: wave w handles f-range [pass*256 + w*64, +64), single g
    int g = pass * 2 + (w >> 1);
    const float* W2g = W2 + g * 1024;
    bf16x8 Ah[2], Al[2];
#pragma unroll
    for (int Mt = 0; Mt < 2; ++Mt) {
      const float* wp = W2g + (Mt * 16 + ll) * 32 + lhi * 8;
      float wv[8];
      *(float4*)&wv[0] = *(const float4*)wp;
      *(float4*)&wv[4] = *(const float4*)(wp + 4);
      unsigned short hh[8], lw[8];
#pragma unroll
      for (int j = 0; j < 8; ++j) {
        unsigned short h = f2bf(wv[j]);
        hh[j] = h;
        lw[j] = f2bf(wv[j] - bf2f(h));
      }
      Ah[Mt] = *(bf16x8*)hh;
      Al[Mt] = *(bf16x8*)lw;
    }
#pragma unroll
    for (int Nt = 0; Nt < 4; ++Nt) {
      int frow = w * 64 + Nt * 16 + ll;                  // local row in X2s
      bf16x8 Bf = *(const bf16x8*)&X2s[frow * 40 + lhi * 8];
      f32x4 accv[2] = {{0.f, 0.f, 0.f, 0.f}, {0.f, 0.f, 0.f, 0.f}};
#pragma unroll
      for (int Mt = 0; Mt < 2; ++Mt) {
        accv[Mt] = __builtin_amdgcn_mfma_f32_16x16x32_bf16(Ah[Mt], Bf, accv[Mt], 0, 0, 0);
        accv[Mt] = __builtin_amdgcn_mfma_f32_16x16x32_bf16(Al[Mt], Bf, accv[Mt], 0, 0, 0);
      }
      int fglob = pass * 256 + frow;
#pragma unroll
      for (int Mt = 0; Mt < 2; ++Mt)
#pragma unroll
        for (int i = 0; i < 4; ++i) {
          int o = Mt * 16 + lhi * 4 + i;
          vb[((size_t)(b * 32 + o) * 64 + p) * 512 + fglob] = f2bf(accv[Mt][i]);
        }
    }
    __syncthreads();
  }
}

// ---- h2T[b,o,f,n] (bf16) = sum_m anorm2[g(f),n,m]*v[b,o,m,f] + b2[o] via MFMA ----
__global__ __launch_bounds__(256) void k5b_h2(const float* __restrict__ b2,
                                              float* __restrict__ ws) {
  __shared__ __align__(16) unsigned short vT[128 * 64];   // rows fl (128B), swizzled
  int b = blockIdx.x, o = blockIdx.y, g = blockIdx.z, t = threadIdx.x;
  const unsigned short* vbp = (const unsigned short*)(ws + OFF_A) +
                              (size_t)(b * 32 + o) * 32768;
  const uint4* vb4 = (const uint4*)vbp;
  unsigned char* vTw = (unsigned char*)vT;
  for (int i = t; i < 1024; i += 256) {
    int p = i >> 4, u = i & 15;
    uint4 val = vb4[p * 64 + g * 16 + u];
    const unsigned short* hv = (const unsigned short*)&val;
#pragma unroll
    for (int e = 0; e < 8; ++e) {
      int fl = u * 8 + e;
      int addr = fl * 128 + ((p * 2) ^ ((((fl & 7) ^ (fl >> 3)) & 7) << 4));
      *(unsigned short*)(vTw + addr) = hv[e];
    }
  }
  int w = t >> 6, l = t & 63, ll = l & 15, lhi = l >> 4;
  const unsigned short* a2h = (const unsigned short*)(ws + OFF_A2H) + g * 4096;
  const unsigned short* a2l = (const unsigned short*)(ws + OFF_A2L) + g * 4096;
  bf16x8 Ah[4][2], Al[4][2];
#pragma unroll
  for (int Mt = 0; Mt < 4; ++Mt)
#pragma unroll
    for (int ks = 0; ks < 2; ++ks) {
      int idx = (Mt * 16 + ll) * 64 + ks * 32 + lhi * 8;
      Ah[Mt][ks] = *(const bf16x8*)(a2h + idx);
      Al[Mt][ks] = *(const bf16x8*)(a2l + idx);
    }
  float bias = b2[o];
  __syncthreads();
  unsigned short* h2T = (unsigned short*)(ws + OFF_B) + (size_t)(b * 32 + o) * 32768;
  const unsigned char* vTr = (const unsigned char*)vT;
#pragma unroll
  for (int fi = 0; fi < 2; ++fi) {
    int fgl = w * 2 + fi;
    int fl = fgl * 16 + ll;
    int swz = (((fl & 7) ^ (fl >> 3)) & 7) << 4;
    bf16x8 Bf[2];
#pragma unroll
    for (int ks = 0; ks < 2; ++ks)
      Bf[ks] = *(const bf16x8*)(vTr + fl * 128 + ((ks * 64 + lhi * 16) ^ swz));
#pragma unroll
    for (int Mt = 0; Mt < 4; ++Mt) {
      f32x4 acc = {0.f, 0.f, 0.f, 0.f};
      acc = __builtin_amdgcn_mfma_f32_16x16x32_bf16(Ah[Mt][0], Bf[0], acc, 0, 0, 0);
      acc = __builtin_amdgcn_mfma_f32_16x16x32_bf16(Al[Mt][0], Bf[0], acc, 0, 0, 0);
      acc = __builtin_amdgcn_mfma_f32_16x16x32_bf16(Ah[Mt][1], Bf[1], acc, 0, 0, 0);
      acc = __builtin_amdgcn_mfma_f32_16x16x32_bf16(Al[Mt][1], Bf[1], acc, 0, 0, 0);
      int f = g * 128 + fgl * 16 + ll;
      int n0 = Mt * 16 + lhi * 4;
      unsigned short hs[4];
#pragma unroll
      for (int i2 = 0; i2 < 4; ++i2) hs[i2] = f2bf(acc[i2] + bias);
      *(short4v*)(h2T + f * 64 + n0) = *(short4v*)hs;
    }
  }
}

// ------- conv2 via bf16 MFMA implicit GEMM + tb2 + relu + mean partial -------
#define L_TWB 66304    // 32 q * 912B = 29184
#define L_RED 95488    // 8 floats
__global__ __launch_bounds__(512) void k6_conv2(const float* __restrict__ tb2,
                                                float* __restrict__ ws) {
  __shared__ __align__(16) unsigned char sm[95520];
  int b = blockIdx.x, c = blockIdx.y, t = threadIdx.x;
  const uint4* h2T4 = (const uint4*)((const unsigned short*)(ws + OFF_B) +
                                     (size_t)(b * 32 + c) * 32768);
  for (int ci = t; ci < 4144; ci += 512) {
    int r = ci >> 3, slot = ci & 7;
    int f = r - 3;
    uint4 val = make_uint4(0u, 0u, 0u, 0u);
    if (f >= 0 && f < 512) val = h2T4[f * 8 + slot];
    *(uint4*)(sm + r * 128 + ((slot ^ (r & 7)) << 4)) = val;
  }
  const uint4* twg = (const uint4*)(ws + OFF_TWB);
  for (int ci = t; ci < 1792; ci += 512) {
    int q = ci / 56, rem = ci - q * 56;
    *(uint4*)(sm + L_TWB + q * 912 + rem * 16) = twg[ci];
  }
  __syncthreads();
  int w = t >> 6, l = t & 63;
  int ll = l & 15, lhi = l >> 4;
  bf16x8 A[2][14];
#pragma unroll
  for (int Mt = 0; Mt < 2; ++Mt)
#pragma unroll
    for (int ks = 0; ks < 14; ++ks) {
      int q = Mt * 16 + ll;
      A[Mt][ks] = *(const bf16x8*)(sm + L_TWB + q * 912 + (ks >> 1) * 128 +
                                   (ks & 1) * 64 + lhi * 16);
    }
  f32x4 zero = {0.f, 0.f, 0.f, 0.f};
  f32x4 acc[2][4];
#pragma unroll
  for (int Mt = 0; Mt < 2; ++Mt)
#pragma unroll
    for (int Nt = 0; Nt < 4; ++Nt) acc[Mt][Nt] = zero;
  int rbase = w * 64 + ll;
#pragma unroll
  for (int ks = 0; ks < 14; ++ks) {
    int rb = rbase + (ks >> 1);
    int x = (((ks & 1) * 4 + lhi) ^ (rb & 7)) << 4;
#pragma unroll
    for (int Nt = 0; Nt < 4; ++Nt) {
      bf16x8 Bf = *(const bf16x8*)(sm + (rb + Nt * 16) * 128 + x);
      acc[0][Nt] = __builtin_amdgcn_mfma_f32_16x16x32_bf16(A[0][ks], Bf, acc[0][Nt], 0, 0, 0);
      acc[1][Nt] = __builtin_amdgcn_mfma_f32_16x16x32_bf16(A[1][ks], Bf, acc[1][Nt], 0, 0, 0);
    }
  }
  float tbv[8];
#pragma unroll
  for (int Mt = 0; Mt < 2; ++Mt)
#pragma unroll
    for (int i = 0; i < 4; ++i) tbv[Mt * 4 + i] = tb2[Mt * 16 + lhi * 4 + i];
  float s = 0.f;
#pragma unroll
  for (int Mt = 0; Mt < 2; ++Mt)
#pragma unroll
    for (int Nt = 0; Nt < 4; ++Nt)
#pragma unroll
      for (int i = 0; i < 4; ++i)
        s += fmaxf(acc[Mt][Nt][i] + tbv[Mt * 4 + i], 0.0f);
#pragma unroll
  for (int off = 32; off > 0; off >>= 1) s += __shfl_down(s, off, 64);
  float* red = (float*)(sm + L_RED);
  if (l == 0) red[w] = s;
  __syncthreads();
  if (t == 0) {
    float tot = 0.f;
    for (int i = 0; i < 8; ++i) tot += red[i];
    ws[OFF_PART + b * 32 + c] = tot;
  }
}

// ---------------- final: feat mean + linear ----------------
__global__ __launch_bounds__(256) void k7_final(const float* __restrict__ Wout,
    const float* __restrict__ bout, const float* __restrict__ ws, float* __restrict__ out) {
  __shared__ float feat[512];
  int t = threadIdx.x;
  for (int i = t; i < 512; i += 256)
    feat[i] = ws[OFF_PART + i] * (1.0f / 16384.0f);
  __syncthreads();
  if (t < 160) {
    int bb = t / 10, j = t - bb * 10;
    float acc = bout[j];
    for (int c = 0; c < 32; ++c) acc += feat[bb * 32 + c] * Wout[j * 32 + c];
    out[t] = acc;
  }
}

extern "C" void kernel_launch(void* const* d_in, const int* in_sizes, int n_in,
                              void* d_out, int out_size, void* d_ws, size_t ws_size,
                              hipStream_t stream) {
  const float* x    = (const float*)d_in[0];
  const float* adj  = (const float*)d_in[1];
  const float* W1   = (const float*)d_in[2];
  const float* b1   = (const float*)d_in[3];
  const float* tw1  = (const float*)d_in[4];
  const float* tb1  = (const float*)d_in[5];
  const float* rp1  = (const float*)d_in[6];
  const float* W2   = (const float*)d_in[7];
  const float* b2   = (const float*)d_in[8];
  const float* tw2  = (const float*)d_in[9];
  const float* tb2  = (const float*)d_in[10];
  // d_in[11] = rp2 : unused (second pooled adjacency is dead in the reference)
  const float* Wout = (const float*)d_in[12];
  const float* bout = (const float*)d_in[13];
  float* out = (float*)d_out;
  float* ws = (float*)d_ws;

  prep1_kernel<<<157, 256, 0, stream>>>(adj, tw1, rp1, tw2, x, ws);
  prep2_kernel<<<384, 256, 0, stream>>>(adj, ws);
  prep3_kernel<<<1216, 256, 0, stream>>>(tw1, ws);
  prep4_kernel<<<4, 256, 0, stream>>>(ws);
  kz_mfma     <<<dim3(16, 9, 4), 512, 0, stream>>>(ws);
  k45m        <<<dim3(16, 64), 256, 0, stream>>>(W1, b1, tb1, W2, ws);
  k5b_h2      <<<dim3(16, 32, 4), 256, 0, stream>>>(b2, ws);
  k6_conv2    <<<dim3(16, 32), 512, 0, stream>>>(tb2, ws);
  k7_final    <<<1, 256, 0, stream>>>(Wout, bout, ws, out);
}